// Round 10
// baseline (83.504 us; speedup 1.0000x reference)
//
#include <hip/hip_runtime.h>
#include <math.h>

// NeRF fused volume renderer, MI355X (gfx950) — MFMA, wave-parallel batches.
// Round 10: r9 structure at 6 blocks/CU, spill-free.
//   * r8 vs r9 isolated the law: occupancy covers the serial chain (r8 37%/53us
//     beat r9 23%/62us despite r8's 8.6MB spill). True peak live = 72 VGPR (r9),
//     so launch_bounds(256,6) (cap 85) gives BOTH: no spill AND 6 blocks/CU.
//   * Grid 1536 persistent (6 blocks/CU, LDS 24.5KB*6 = 147KB < 160KB).
//   * Trailing barrier removed: sPdB is same-wave-only; sRed double-buffered
//     by iteration parity -> one __syncthreads per ray-iteration.
//   * Batch factoring (exact): P_total = P_b0 + exp(-S0) * P_b1.
// Layouts (m89-verified / ISA doc): C/D col=lane&15, row=(lane>>4)*4+reg;
// x32 A/B k=(lane>>4)*8+e; x16 A/B k=(lane>>4)*4+e.

typedef _Float16 f16x8 __attribute__((ext_vector_type(8)));
typedef _Float16 f16x4 __attribute__((ext_vector_type(4)));
typedef float f32x4 __attribute__((ext_vector_type(4)));

static constexpr float STEPf = 0.040594940802395566f; // 3*sqrt(3)/128 in f32

static __device__ __forceinline__ unsigned pk2(float a, float b) {
    return __builtin_bit_cast(unsigned, __builtin_amdgcn_cvt_pkrtz(a, b));
}
static __device__ __forceinline__ f16x8 mk8(unsigned a, unsigned b, unsigned c, unsigned d) {
    uint4 u = make_uint4(a, b, c, d);
    return __builtin_bit_cast(f16x8, u);
}
static __device__ __forceinline__ f16x4 pkh(const f32x4 c) {
    uint2 u;
    u.x = pk2(fmaxf(c[0], 0.f), fmaxf(c[1], 0.f));
    u.y = pk2(fmaxf(c[2], 0.f), fmaxf(c[3], 0.f));
    return __builtin_bit_cast(f16x4, u);
}

extern "C" __global__ void __launch_bounds__(256, 6)
nerf_mfma(const float* __restrict__ rays_o, const float* __restrict__ viewdirs,
          const void* __restrict__ occ,
          const float* __restrict__ W1g, const float* __restrict__ b1g,
          const float* __restrict__ W2g, const float* __restrict__ b2g,
          const float* __restrict__ Wsg, const float* __restrict__ bsg,
          const float* __restrict__ Wcg, const float* __restrict__ Wdg,
          const float* __restrict__ bcg, const float* __restrict__ Wrg,
          const float* __restrict__ brg,
          float* __restrict__ out, int nrays)
{
    __shared__ __align__(16) unsigned char sW1[64 * 64];
    __shared__ __align__(16) unsigned char sW2[64 * 128];
    __shared__ __align__(16) unsigned char sWc[64 * 128];
    __shared__ __align__(16) unsigned char sHC[16 * 128];
    __shared__ __align__(16) float sWs[64];
    __shared__ __align__(16) float sB1[64], sB2[64];
    __shared__ __align__(16) float sPdB[4][64];
    __shared__ __align__(16) float sRed[2][4][6];  // parity-buffered {aW,aWT,aR,aG,aB,S}
    __shared__ int sKind;

    const int tid = threadIdx.x;

    // ---------------- staging: COALESCED global reads, swizzled LDS writes ----
    for (int idx = tid; idx < 1024; idx += 256)             // zero sW1 (covers k-pad)
        ((uint32_t*)sW1)[idx] = 0u;
    __syncthreads();                                        // pad-zero before scatter
    for (int idx = tid; idx < 27 * 64; idx += 256) {        // W1, linear in memory
        const int k = idx >> 6, h = idx & 63;
        *(_Float16*)(sW1 + h * 64 + (((k >> 3) ^ (h & 3)) << 4) + ((k & 7) << 1)) =
            (_Float16)W1g[idx];
    }
    for (int idx = tid; idx < 64 * 64; idx += 256) {        // W2, Wc, linear
        const int k = idx >> 6, h = idx & 63;
        const int off = h * 128 + ((((k >> 2) ^ ((h & 7) << 1)) << 3)) + ((k & 3) << 1);
        *(_Float16*)(sW2 + off) = (_Float16)W2g[idx];
        *(_Float16*)(sWc + off) = (_Float16)Wcg[idx];
    }
    for (int idx = tid; idx < 192; idx += 256) {            // rgb head rows, linear
        const int kk = idx / 3, c = idx - 3 * kk;
        const _Float16 v = (_Float16)Wrg[idx];
        #pragma unroll
        for (int r = 0; r < 16; ++r) {
            if ((r % 3) == c) {
                const int off = r * 128 + ((((kk >> 2) ^ ((r & 7) << 1)) << 3)) + ((kk & 3) << 1);
                *(_Float16*)(sHC + off) = v;
            }
        }
    }
    if (tid < 64) {
        sB1[tid] = b1g[tid]; sB2[tid] = b2g[tid];
        sWs[tid] = Wsg[tid];
    }
    if (tid == 0) {   // sniff occ dtype: 0=u8, 1=i32, 2=f32
        const int*   oi = (const int*)occ;
        const float* of = (const float*)occ;
        bool i32ok = true, f32ok = true;
        for (int k = 0; k < 64; ++k) {
            if (oi[k] != 0 && oi[k] != 1) i32ok = false;
            const float f = of[k];
            if (!(f == 0.f || f == 1.f)) f32ok = false;
        }
        sKind = i32ok ? 1 : (f32ok ? 2 : 0);
    }
    __syncthreads();

    const int lane = tid & 63;
    const int wid  = tid >> 6;
    const int bat  = wid & 1;         // batch this wave owns
    const int pr   = wid >> 1;        // ray slot within block (0/1)
    const int kind = sKind;
    const int lh = lane & 15, g = lane >> 4;
    const int swz8 = (lh & 7) << 1;

    const float bsV = bsg[0];
    const float br0 = brg[0], br1 = brg[1], br2 = brg[2];

    const int baseStride = (int)(gridDim.x << 1);
    int par = 0;
    for (int base = (int)(blockIdx.x << 1); base < nrays; base += baseStride, par ^= 1) {
        const int ray = base + pr;
        const bool haveRay = ray < nrays;

        float aW = 0.f, aWT = 0.f, aR = 0.f, aG = 0.f, aB = 0.f, Ssum = 0.f;

        if (haveRay) {
            const float ox = rays_o[ray * 3 + 0], oy = rays_o[ray * 3 + 1], oz = rays_o[ray * 3 + 2];
            const float dxv = viewdirs[ray * 3 + 0], dyv = viewdirs[ray * 3 + 1], dzv = viewdirs[ray * 3 + 2];
            const float sdx = fabsf(dxv) < 1e-8f ? 1e-8f : dxv;
            const float sdy = fabsf(dyv) < 1e-8f ? 1e-8f : dyv;
            const float sdz = fabsf(dzv) < 1e-8f ? 1e-8f : dzv;
            const float t1x = (-1.5f - ox) / sdx, t2x = (1.5f - ox) / sdx;
            const float t1y = (-1.5f - oy) / sdy, t2y = (1.5f - oy) / sdy;
            const float t1z = (-1.5f - oz) / sdz, t2z = (1.5f - oz) / sdz;
            const float t_near = fmaxf(fmaxf(fminf(t1x, t2x), fminf(t1y, t2y)),
                                       fmaxf(fminf(t1z, t2z), 0.f));
            const float t_far  = fminf(fminf(fmaxf(t1x, t2x), fmaxf(t1y, t2y)), fmaxf(t1z, t2z));

            // per-ray dir posenc -> sPdB[wid][j] (same-wave write+read: no barrier)
            {
                float ped[15];
                ped[0] = dxv; ped[1] = dyv; ped[2] = dzv;
                const float dc[3] = {dxv, dyv, dzv};
                #pragma unroll
                for (int c = 0; c < 3; ++c) {
                    float s1, c1;
                    __sincosf(dc[c], &s1, &c1);
                    ped[3 + c * 4 + 0] = s1;
                    ped[3 + c * 4 + 1] = 2.f * s1 * c1;
                    ped[3 + c * 4 + 2] = c1;
                    ped[3 + c * 4 + 3] = 1.f - 2.f * s1 * s1;
                }
                float pd = 0.f;
                #pragma unroll
                for (int i = 0; i < 15; ++i) pd += ped[i] * Wdg[i * 64 + lane];
                sPdB[wid][lane] = pd + bcg[lane];
            }

            // ---- own-sample validity + occupancy gather ----
            const float tS = t_near + ((float)((bat << 6) | lane) + 0.5f) * STEPf;
            const bool in_seg = tS < t_far;
            bool valid;
            {
                const float px = ox + dxv * tS, py = oy + dyv * tS, pz = oz + dzv * tS;
                const float cx = (px + 1.5f) * (128.f / 3.f);
                const float cy = (py + 1.5f) * (128.f / 3.f);
                const float cz = (pz + 1.5f) * (128.f / 3.f);
                const bool in_box = (cx >= 0.f) & (cx < 128.f) & (cy >= 0.f) & (cy < 128.f)
                                  & (cz >= 0.f) & (cz < 128.f);
                const int ix = min(max((int)floorf(cx), 0), 127);
                const int iy = min(max((int)floorf(cy), 0), 127);
                const int iz = min(max((int)floorf(cz), 0), 127);
                const int ci = (ix << 14) | (iy << 7) | iz;
                bool occv;
                if (kind == 1)      occv = ((const int*)occ)[ci] != 0;
                else if (kind == 2) occv = ((const float*)occ)[ci] != 0.f;
                else                occv = ((const unsigned char*)occ)[ci] != 0;
                valid = in_seg & in_box & occv;
            }

            if (__ballot(valid) != 0ULL) {
                // ---- posenc in x32-B layout (lane: feats 8g..8g+7, samples 16nt+lh) ----
                f16x8 bx[4];
                #pragma unroll
                for (int nt = 0; nt < 4; ++nt) {
                    const float ts = t_near + ((float)((bat << 6) + (nt << 4) + lh) + 0.5f) * STEPf;
                    const float qx = ox + dxv * ts, qy = oy + dyv * ts, qz = oz + dzv * ts;
                    const float u = (g < 2) ? qx : ((g == 2) ? qy : qz);
                    const float v = (g == 1) ? qy : ((g == 2) ? qz : 0.f);
                    float su1, cu1, sv1, cv1;
                    __sincosf(u, &su1, &cu1);
                    __sincosf(v, &sv1, &cv1);
                    const float su2 = 2.f * su1 * cu1, cu2 = 1.f - 2.f * su1 * su1;
                    const float su4 = 2.f * su2 * cu2, cu4 = 1.f - 2.f * su2 * su2;
                    const float su8 = 2.f * su4 * cu4, cu8 = 1.f - 2.f * su4 * su4;
                    const float sv2 = 2.f * sv1 * cv1, cv2 = 1.f - 2.f * sv1 * sv1;
                    const float sv4 = 2.f * sv2 * cv2, cv4 = 1.f - 2.f * sv2 * sv2;
                    const float sv8 = 2.f * sv4 * cv4;
                    const bool g0 = (g == 0);
                    const float f0 = g0 ? qx : cu2;
                    const float f1 = g0 ? qy : cu4;
                    const float f2 = g0 ? qz : cu8;
                    const float f3 = g0 ? su1 : sv1;
                    const float f4 = g0 ? su2 : sv2;
                    const float f5 = g0 ? su4 : sv4;
                    const float f6 = g0 ? su8 : sv8;
                    const float f7 = g0 ? cu1 : ((g == 3) ? 0.f : cv1);
                    bx[nt] = mk8(pk2(f0, f1), pk2(f2, f3), pk2(f4, f5), pk2(f6, f7));
                }

                // ---- L1 (16x16x32): bias as C ----
                f16x4 bh1[4][4];
                #pragma unroll
                for (int mt = 0; mt < 4; ++mt) {
                    const f32x4 bf = *(const f32x4*)&sB1[16 * mt + 4 * g];
                    const f16x8 a = *(const f16x8*)(sW1 + (16 * mt + lh) * 64 + ((g ^ (lh & 3)) << 4));
                    #pragma unroll
                    for (int nt = 0; nt < 4; ++nt) {
                        f32x4 c = __builtin_amdgcn_mfma_f32_16x16x32_f16(a, bx[nt], bf, 0, 0, 0);
                        bh1[mt][nt] = pkh(c);   // D rows 4g+r == B k 4g+e for k-step mt
                    }
                }
                // ---- L2 (4 x 16x16x16 per tile) + fused VALU sigma partials ----
                f16x4 bh2[4][4];
                float sp[4] = {0.f, 0.f, 0.f, 0.f};
                #pragma unroll
                for (int mt = 0; mt < 4; ++mt) {
                    const int row = (16 * mt + lh) * 128;
                    f16x4 a0 = *(const f16x4*)(sW2 + row + (((0 + g) ^ swz8) << 3));
                    f16x4 a1 = *(const f16x4*)(sW2 + row + (((4 + g) ^ swz8) << 3));
                    f16x4 a2 = *(const f16x4*)(sW2 + row + (((8 + g) ^ swz8) << 3));
                    f16x4 a3 = *(const f16x4*)(sW2 + row + (((12 + g) ^ swz8) << 3));
                    const f32x4 bf = *(const f32x4*)&sB2[16 * mt + 4 * g];
                    const f32x4 ws = *(const f32x4*)&sWs[16 * mt + 4 * g];
                    #pragma unroll
                    for (int nt = 0; nt < 4; ++nt) {
                        f32x4 c = __builtin_amdgcn_mfma_f32_16x16x16f16(a0, bh1[0][nt], bf, 0, 0, 0);
                        c = __builtin_amdgcn_mfma_f32_16x16x16f16(a1, bh1[1][nt], c, 0, 0, 0);
                        c = __builtin_amdgcn_mfma_f32_16x16x16f16(a2, bh1[2][nt], c, 0, 0, 0);
                        c = __builtin_amdgcn_mfma_f32_16x16x16f16(a3, bh1[3][nt], c, 0, 0, 0);
                        const float r0 = fmaxf(c[0], 0.f), r1 = fmaxf(c[1], 0.f);
                        const float r2 = fmaxf(c[2], 0.f), r3 = fmaxf(c[3], 0.f);
                        sp[nt] += ws[0] * r0 + ws[1] * r1 + ws[2] * r2 + ws[3] * r3;
                        uint2 u; u.x = pk2(r0, r1); u.y = pk2(r2, r3);
                        bh2[mt][nt] = __builtin_bit_cast(f16x4, u);
                    }
                }
                // ---- Wc layer (C = pd + bc) + FUSED rgb head (bgf single-mt live) ----
                f32x4 accC[4];
                #pragma unroll
                for (int mt = 0; mt < 4; ++mt) {
                    const int row = (16 * mt + lh) * 128;
                    f16x4 a0 = *(const f16x4*)(sWc + row + (((0 + g) ^ swz8) << 3));
                    f16x4 a1 = *(const f16x4*)(sWc + row + (((4 + g) ^ swz8) << 3));
                    f16x4 a2 = *(const f16x4*)(sWc + row + (((8 + g) ^ swz8) << 3));
                    f16x4 a3 = *(const f16x4*)(sWc + row + (((12 + g) ^ swz8) << 3));
                    const f32x4 pdf = *(const f32x4*)&sPdB[wid][16 * mt + 4 * g];
                    const f16x4 aC = *(const f16x4*)(sHC + lh * 128 + (((4 * mt + g) ^ swz8) << 3));
                    #pragma unroll
                    for (int nt = 0; nt < 4; ++nt) {
                        f32x4 c = __builtin_amdgcn_mfma_f32_16x16x16f16(a0, bh2[0][nt], pdf, 0, 0, 0);
                        c = __builtin_amdgcn_mfma_f32_16x16x16f16(a1, bh2[1][nt], c, 0, 0, 0);
                        c = __builtin_amdgcn_mfma_f32_16x16x16f16(a2, bh2[2][nt], c, 0, 0, 0);
                        c = __builtin_amdgcn_mfma_f32_16x16x16f16(a3, bh2[3][nt], c, 0, 0, 0);
                        const f16x4 bgf = pkh(c);
                        f32x4 ca = (mt == 0) ? f32x4{0.f, 0.f, 0.f, 0.f} : accC[nt];
                        accC[nt] = __builtin_amdgcn_mfma_f32_16x16x16f16(aC, bgf, ca, 0, 0, 0);
                    }
                }
                // ---- sigma reduce over g-groups + own-sample selects ----
                #pragma unroll
                for (int nt = 0; nt < 4; ++nt) {
                    sp[nt] += __shfl_xor(sp[nt], 16);
                    sp[nt] += __shfl_xor(sp[nt], 32);
                }
                const float sraw = (g == 0) ? sp[0] : (g == 1) ? sp[1]
                                 : (g == 2) ? sp[2] : sp[3];
                const float crS  = (g == 0) ? accC[0][0] : (g == 1) ? accC[1][2]
                                 : (g == 2) ? accC[2][1] : accC[3][0];
                const float cgS  = (g == 0) ? accC[0][1] : (g == 1) ? accC[1][0]
                                 : (g == 2) ? accC[2][2] : accC[3][1];
                const float cbS  = (g == 0) ? accC[0][2] : (g == 1) ? accC[1][1]
                                 : (g == 2) ? accC[2][0] : accC[3][2];

                const float sigma = valid ? fmaxf(sraw + bsV, 0.f) : 0.f;
                const float rC = 1.f / (1.f + __expf(-(crS + br0)));
                const float gC = 1.f / (1.f + __expf(-(cgS + br1)));
                const float bC = 1.f / (1.f + __expf(-(cbS + br2)));

                // ---- compositing with carry = 0 (exact factoring: see header) ----
                const float sdelta = sigma * STEPf;
                float scan = sdelta;
                #pragma unroll
                for (int off = 1; off < 64; off <<= 1) {
                    const float n = __shfl_up(scan, off);
                    if (lane >= off) scan += n;
                }
                const float T     = __expf(-(scan - sdelta));
                const float alpha = 1.f - __expf(-sdelta);
                const float w = T * alpha;
                aW  = w;
                aWT = w * tS;
                aR  = w * rC;
                aG  = w * gC;
                aB  = w * bC;
                Ssum = __shfl(scan, 63);
            }
        }

        // ---- wave-reduce the five accumulators ----
        #pragma unroll
        for (int off = 32; off; off >>= 1) {
            aW  += __shfl_xor(aW,  off);
            aWT += __shfl_xor(aWT, off);
            aR  += __shfl_xor(aR,  off);
            aG  += __shfl_xor(aG,  off);
            aB  += __shfl_xor(aB,  off);
        }
        if (lane == 0) {
            sRed[par][wid][0] = aW;  sRed[par][wid][1] = aWT; sRed[par][wid][2] = aR;
            sRed[par][wid][3] = aG;  sRed[par][wid][4] = aB;  sRed[par][wid][5] = Ssum;
        }
        __syncthreads();
        if (haveRay && bat == 0 && lane == 0) {
            const float f = __expf(-Ssum);           // exp(-S0): batch-1 scale
            const float W1a = aW  + f * sRed[par][wid | 1][0];
            const float WTa = aWT + f * sRed[par][wid | 1][1];
            const float Ra  = aR  + f * sRed[par][wid | 1][2];
            const float Ga  = aG  + f * sRed[par][wid | 1][3];
            const float Ba  = aB  + f * sRed[par][wid | 1][4];
            const float bg_ = 1.f - W1a;
            out[ray * 3 + 0] = Ra + bg_;
            out[ray * 3 + 1] = Ga + bg_;
            out[ray * 3 + 2] = Ba + bg_;
            out[3 * nrays + ray] = WTa;
            out[4 * nrays + ray] = W1a;
        }
        // no trailing barrier: next iteration writes sRed[par^1]; sPdB is same-wave
    }
}

extern "C" void kernel_launch(void* const* d_in, const int* in_sizes, int n_in,
                              void* d_out, int out_size, void* d_ws, size_t ws_size,
                              hipStream_t stream) {
    const float* rays_o   = (const float*)d_in[0];
    const float* viewdirs = (const float*)d_in[1];
    const void*  occ      = (const void*) d_in[2];
    const float* W1 = (const float*)d_in[3];
    const float* b1 = (const float*)d_in[4];
    const float* W2 = (const float*)d_in[5];
    const float* b2 = (const float*)d_in[6];
    const float* Ws = (const float*)d_in[7];
    const float* bs = (const float*)d_in[8];
    const float* Wc = (const float*)d_in[9];
    const float* Wd = (const float*)d_in[10];
    const float* bc = (const float*)d_in[11];
    const float* Wr = (const float*)d_in[12];
    const float* br = (const float*)d_in[13];
    float* out = (float*)d_out;

    const int nrays = in_sizes[0] / 3;
    int nblocks = 1536;                      // persistent: 6 blocks/CU, grid-stride
    const int needed = (nrays + 1) / 2;      // 2 rays per block
    if (needed < nblocks) nblocks = needed;

    nerf_mfma<<<nblocks, 256, 0, stream>>>(rays_o, viewdirs, occ,
                                           W1, b1, W2, b2, Ws, bs, Wc, Wd, bc, Wr, br,
                                           out, nrays);
}

// Round 11
// 68.403 us; speedup vs baseline: 1.2208x; 1.2208x over previous
//
#include <hip/hip_runtime.h>
#include <math.h>

// NeRF fused volume renderer, MI355X (gfx950) — MFMA, 8-wave-per-ray.
// Round 11: wave = (batch, 16-sample column tile). Block = 512 thr = 8 waves = 1 ray.
//   r6-r10 law: the VGPR allocator lands on a wave-count breakpoint AT/BELOW the
//   launch_bounds cap and spills to get there (cap128->64+8.6MB, cap85->40+145MB).
//   Fix: make natural peak live <= 64 by giving each wave ONE column tile (nt):
//   bh1[4]+bh2[4]+bx+accC+scalars ~= 60 VGPR. No occupancy hint (natural alloc).
//   Compositing factors exactly per 16-sample tile: P = sum_i (prod_{j<i} e^-Sj) Pi.
//   8 partials {aW,aWT,aR,aG,aB,S} in LDS; wave 0 combines.
// Layouts (m89-verified / ISA doc): C/D col=lane&15, row=(lane>>4)*4+reg;
// x32 A/B k=(lane>>4)*8+e; x16 A/B k=(lane>>4)*4+e.

typedef _Float16 f16x8 __attribute__((ext_vector_type(8)));
typedef _Float16 f16x4 __attribute__((ext_vector_type(4)));
typedef float f32x4 __attribute__((ext_vector_type(4)));

static constexpr float STEPf = 0.040594940802395566f; // 3*sqrt(3)/128 in f32

static __device__ __forceinline__ unsigned pk2(float a, float b) {
    return __builtin_bit_cast(unsigned, __builtin_amdgcn_cvt_pkrtz(a, b));
}
static __device__ __forceinline__ f16x8 mk8(unsigned a, unsigned b, unsigned c, unsigned d) {
    uint4 u = make_uint4(a, b, c, d);
    return __builtin_bit_cast(f16x8, u);
}
static __device__ __forceinline__ f16x4 pkh(const f32x4 c) {
    uint2 u;
    u.x = pk2(fmaxf(c[0], 0.f), fmaxf(c[1], 0.f));
    u.y = pk2(fmaxf(c[2], 0.f), fmaxf(c[3], 0.f));
    return __builtin_bit_cast(f16x4, u);
}

extern "C" __global__ void __launch_bounds__(512)
nerf_mfma(const float* __restrict__ rays_o, const float* __restrict__ viewdirs,
          const void* __restrict__ occ,
          const float* __restrict__ W1g, const float* __restrict__ b1g,
          const float* __restrict__ W2g, const float* __restrict__ b2g,
          const float* __restrict__ Wsg, const float* __restrict__ bsg,
          const float* __restrict__ Wcg, const float* __restrict__ Wdg,
          const float* __restrict__ bcg, const float* __restrict__ Wrg,
          const float* __restrict__ brg,
          float* __restrict__ out, int nrays)
{
    __shared__ __align__(16) unsigned char sW1[64 * 64];
    __shared__ __align__(16) unsigned char sW2[64 * 128];
    __shared__ __align__(16) unsigned char sWc[64 * 128];
    __shared__ __align__(16) unsigned char sHC[16 * 128];
    __shared__ __align__(16) float sWs[64];
    __shared__ __align__(16) float sB1[64], sB2[64];
    __shared__ __align__(16) float sPdB[8][64];
    __shared__ __align__(16) float sRed[2][8][6];  // parity x wave x {aW,aWT,aR,aG,aB,S}
    __shared__ int sKind;

    const int tid = threadIdx.x;   // 0..511

    // ---------------- staging: COALESCED global reads, swizzled LDS writes ----
    for (int idx = tid; idx < 1024; idx += 512)             // zero sW1 (covers k-pad)
        ((uint32_t*)sW1)[idx] = 0u;
    __syncthreads();                                        // pad-zero before scatter
    for (int idx = tid; idx < 27 * 64; idx += 512) {        // W1, linear in memory
        const int k = idx >> 6, h = idx & 63;
        *(_Float16*)(sW1 + h * 64 + (((k >> 3) ^ (h & 3)) << 4) + ((k & 7) << 1)) =
            (_Float16)W1g[idx];
    }
    for (int idx = tid; idx < 64 * 64; idx += 512) {        // W2, Wc, linear
        const int k = idx >> 6, h = idx & 63;
        const int off = h * 128 + ((((k >> 2) ^ ((h & 7) << 1)) << 3)) + ((k & 3) << 1);
        *(_Float16*)(sW2 + off) = (_Float16)W2g[idx];
        *(_Float16*)(sWc + off) = (_Float16)Wcg[idx];
    }
    for (int idx = tid; idx < 192; idx += 512) {            // rgb head rows, linear
        const int kk = idx / 3, c = idx - 3 * kk;
        const _Float16 v = (_Float16)Wrg[idx];
        #pragma unroll
        for (int r = 0; r < 16; ++r) {
            if ((r % 3) == c) {
                const int off = r * 128 + ((((kk >> 2) ^ ((r & 7) << 1)) << 3)) + ((kk & 3) << 1);
                *(_Float16*)(sHC + off) = v;
            }
        }
    }
    if (tid < 64) {
        sB1[tid] = b1g[tid]; sB2[tid] = b2g[tid];
        sWs[tid] = Wsg[tid];
    }
    if (tid == 0) {   // sniff occ dtype: 0=u8, 1=i32, 2=f32
        const int*   oi = (const int*)occ;
        const float* of = (const float*)occ;
        bool i32ok = true, f32ok = true;
        for (int k = 0; k < 64; ++k) {
            if (oi[k] != 0 && oi[k] != 1) i32ok = false;
            const float f = of[k];
            if (!(f == 0.f || f == 1.f)) f32ok = false;
        }
        sKind = i32ok ? 1 : (f32ok ? 2 : 0);
    }
    __syncthreads();

    const int lane = tid & 63;
    const int wid  = tid >> 6;        // 0..7; sample range order index == wid
    const int bat  = wid >> 2;        // batch 0/1
    const int nt   = wid & 3;         // column tile within batch
    const int kind = sKind;
    const int lh = lane & 15, g = lane >> 4;
    const int swz8 = (lh & 7) << 1;

    const float bsV = bsg[0];
    const float br0 = brg[0], br1 = brg[1], br2 = brg[2];

    int par = 0;
    for (int ray = (int)blockIdx.x; ray < nrays; ray += (int)gridDim.x, par ^= 1) {

        const float ox = rays_o[ray * 3 + 0], oy = rays_o[ray * 3 + 1], oz = rays_o[ray * 3 + 2];
        const float dxv = viewdirs[ray * 3 + 0], dyv = viewdirs[ray * 3 + 1], dzv = viewdirs[ray * 3 + 2];
        const float sdx = fabsf(dxv) < 1e-8f ? 1e-8f : dxv;
        const float sdy = fabsf(dyv) < 1e-8f ? 1e-8f : dyv;
        const float sdz = fabsf(dzv) < 1e-8f ? 1e-8f : dzv;
        const float t1x = (-1.5f - ox) / sdx, t2x = (1.5f - ox) / sdx;
        const float t1y = (-1.5f - oy) / sdy, t2y = (1.5f - oy) / sdy;
        const float t1z = (-1.5f - oz) / sdz, t2z = (1.5f - oz) / sdz;
        const float t_near = fmaxf(fmaxf(fminf(t1x, t2x), fminf(t1y, t2y)),
                                   fmaxf(fminf(t1z, t2z), 0.f));
        const float t_far  = fminf(fminf(fmaxf(t1x, t2x), fmaxf(t1y, t2y)), fmaxf(t1z, t2z));

        float aW = 0.f, aWT = 0.f, aR = 0.f, aG = 0.f, aB = 0.f, Ssum = 0.f;

        // own sample: s = 64*bat + 16*nt + lh  (wid-ordered contiguous 16-ranges)
        const float tS = t_near + ((float)((bat << 6) | (nt << 4) | lh) + 0.5f) * STEPf;
        const bool in_seg = tS < t_far;

        if (__ballot(in_seg) != 0ULL) {
            // per-ray dir posenc -> sPdB[wid][j] (same-wave write+read: no barrier)
            {
                float ped[15];
                ped[0] = dxv; ped[1] = dyv; ped[2] = dzv;
                const float dc[3] = {dxv, dyv, dzv};
                #pragma unroll
                for (int c = 0; c < 3; ++c) {
                    float s1, c1;
                    __sincosf(dc[c], &s1, &c1);
                    ped[3 + c * 4 + 0] = s1;
                    ped[3 + c * 4 + 1] = 2.f * s1 * c1;
                    ped[3 + c * 4 + 2] = c1;
                    ped[3 + c * 4 + 3] = 1.f - 2.f * s1 * s1;
                }
                float pd = 0.f;
                #pragma unroll
                for (int i = 0; i < 15; ++i) pd += ped[i] * Wdg[i * 64 + lane];
                sPdB[wid][lane] = pd + bcg[lane];
            }

            // ---- own-sample validity (occ gather; 4 g-lanes share an address) ----
            bool valid;
            {
                const float px = ox + dxv * tS, py = oy + dyv * tS, pz = oz + dzv * tS;
                const float cx = (px + 1.5f) * (128.f / 3.f);
                const float cy = (py + 1.5f) * (128.f / 3.f);
                const float cz = (pz + 1.5f) * (128.f / 3.f);
                const bool in_box = (cx >= 0.f) & (cx < 128.f) & (cy >= 0.f) & (cy < 128.f)
                                  & (cz >= 0.f) & (cz < 128.f);
                const int ix = min(max((int)floorf(cx), 0), 127);
                const int iy = min(max((int)floorf(cy), 0), 127);
                const int iz = min(max((int)floorf(cz), 0), 127);
                const int ci = (ix << 14) | (iy << 7) | iz;
                bool occv;
                if (kind == 1)      occv = ((const int*)occ)[ci] != 0;
                else if (kind == 2) occv = ((const float*)occ)[ci] != 0.f;
                else                occv = ((const unsigned char*)occ)[ci] != 0;
                valid = in_seg & in_box & occv;
            }

            if (__ballot(valid) != 0ULL) {
                // ---- posenc in x32-B layout: lane computes feats 8g..8g+7 of
                //      its own sample (col lh) ----
                f16x8 bx;
                {
                    const float qx = ox + dxv * tS, qy = oy + dyv * tS, qz = oz + dzv * tS;
                    const float u = (g < 2) ? qx : ((g == 2) ? qy : qz);
                    const float v = (g == 1) ? qy : ((g == 2) ? qz : 0.f);
                    float su1, cu1, sv1, cv1;
                    __sincosf(u, &su1, &cu1);
                    __sincosf(v, &sv1, &cv1);
                    const float su2 = 2.f * su1 * cu1, cu2 = 1.f - 2.f * su1 * su1;
                    const float su4 = 2.f * su2 * cu2, cu4 = 1.f - 2.f * su2 * su2;
                    const float su8 = 2.f * su4 * cu4, cu8 = 1.f - 2.f * su4 * su4;
                    const float sv2 = 2.f * sv1 * cv1, cv2 = 1.f - 2.f * sv1 * sv1;
                    const float sv4 = 2.f * sv2 * cv2, cv4 = 1.f - 2.f * sv2 * sv2;
                    const float sv8 = 2.f * sv4 * cv4;
                    const bool g0 = (g == 0);
                    const float f0 = g0 ? qx : cu2;
                    const float f1 = g0 ? qy : cu4;
                    const float f2 = g0 ? qz : cu8;
                    const float f3 = g0 ? su1 : sv1;
                    const float f4 = g0 ? su2 : sv2;
                    const float f5 = g0 ? su4 : sv4;
                    const float f6 = g0 ? su8 : sv8;
                    const float f7 = g0 ? cu1 : ((g == 3) ? 0.f : cv1);
                    bx = mk8(pk2(f0, f1), pk2(f2, f3), pk2(f4, f5), pk2(f6, f7));
                }

                // ---- L1 (16x16x32): bias as C ----
                f16x4 bh1[4];
                #pragma unroll
                for (int mt = 0; mt < 4; ++mt) {
                    const f32x4 bf = *(const f32x4*)&sB1[16 * mt + 4 * g];
                    const f16x8 a = *(const f16x8*)(sW1 + (16 * mt + lh) * 64 + ((g ^ (lh & 3)) << 4));
                    f32x4 c = __builtin_amdgcn_mfma_f32_16x16x32_f16(a, bx, bf, 0, 0, 0);
                    bh1[mt] = pkh(c);   // D rows 4g+r == B k 4g+e for k-step mt
                }
                // ---- L2 (4 x 16x16x16) + fused VALU sigma partial ----
                f16x4 bh2[4];
                float sp = 0.f;
                #pragma unroll
                for (int mt = 0; mt < 4; ++mt) {
                    const int row = (16 * mt + lh) * 128;
                    const f16x4 a0 = *(const f16x4*)(sW2 + row + (((0 + g) ^ swz8) << 3));
                    const f16x4 a1 = *(const f16x4*)(sW2 + row + (((4 + g) ^ swz8) << 3));
                    const f16x4 a2 = *(const f16x4*)(sW2 + row + (((8 + g) ^ swz8) << 3));
                    const f16x4 a3 = *(const f16x4*)(sW2 + row + (((12 + g) ^ swz8) << 3));
                    const f32x4 bf = *(const f32x4*)&sB2[16 * mt + 4 * g];
                    const f32x4 ws = *(const f32x4*)&sWs[16 * mt + 4 * g];
                    f32x4 c = __builtin_amdgcn_mfma_f32_16x16x16f16(a0, bh1[0], bf, 0, 0, 0);
                    c = __builtin_amdgcn_mfma_f32_16x16x16f16(a1, bh1[1], c, 0, 0, 0);
                    c = __builtin_amdgcn_mfma_f32_16x16x16f16(a2, bh1[2], c, 0, 0, 0);
                    c = __builtin_amdgcn_mfma_f32_16x16x16f16(a3, bh1[3], c, 0, 0, 0);
                    const float r0 = fmaxf(c[0], 0.f), r1 = fmaxf(c[1], 0.f);
                    const float r2 = fmaxf(c[2], 0.f), r3 = fmaxf(c[3], 0.f);
                    sp += ws[0] * r0 + ws[1] * r1 + ws[2] * r2 + ws[3] * r3;
                    uint2 u; u.x = pk2(r0, r1); u.y = pk2(r2, r3);
                    bh2[mt] = __builtin_bit_cast(f16x4, u);
                }
                // ---- Wc layer (C = pd + bc) + FUSED rgb head ----
                f32x4 accC;
                #pragma unroll
                for (int mt = 0; mt < 4; ++mt) {
                    const int row = (16 * mt + lh) * 128;
                    const f16x4 a0 = *(const f16x4*)(sWc + row + (((0 + g) ^ swz8) << 3));
                    const f16x4 a1 = *(const f16x4*)(sWc + row + (((4 + g) ^ swz8) << 3));
                    const f16x4 a2 = *(const f16x4*)(sWc + row + (((8 + g) ^ swz8) << 3));
                    const f16x4 a3 = *(const f16x4*)(sWc + row + (((12 + g) ^ swz8) << 3));
                    const f32x4 pdf = *(const f32x4*)&sPdB[wid][16 * mt + 4 * g];
                    const f16x4 aC = *(const f16x4*)(sHC + lh * 128 + (((4 * mt + g) ^ swz8) << 3));
                    f32x4 c = __builtin_amdgcn_mfma_f32_16x16x16f16(a0, bh2[0], pdf, 0, 0, 0);
                    c = __builtin_amdgcn_mfma_f32_16x16x16f16(a1, bh2[1], c, 0, 0, 0);
                    c = __builtin_amdgcn_mfma_f32_16x16x16f16(a2, bh2[2], c, 0, 0, 0);
                    c = __builtin_amdgcn_mfma_f32_16x16x16f16(a3, bh2[3], c, 0, 0, 0);
                    const f16x4 bgf = pkh(c);
                    f32x4 ca = (mt == 0) ? f32x4{0.f, 0.f, 0.f, 0.f} : accC;
                    accC = __builtin_amdgcn_mfma_f32_16x16x16f16(aC, bgf, ca, 0, 0, 0);
                }
                // ---- sigma reduce over g-groups (all lanes get full sum) ----
                sp += __shfl_xor(sp, 16);
                sp += __shfl_xor(sp, 32);
                // ---- rgb extraction: row 4g+j has color (g+j)%3 -> j=(c-g) mod 3 ----
                const float crS = (g == 1) ? accC[2] : (g == 2) ? accC[1] : accC[0];
                const float cgS = (g == 0) ? accC[1] : (g == 1) ? accC[0]
                                : (g == 2) ? accC[2] : accC[1];
                const float cbS = (g == 0) ? accC[2] : (g == 1) ? accC[1]
                                : (g == 2) ? accC[0] : accC[2];

                const float sigma = valid ? fmaxf(sp + bsV, 0.f) : 0.f;
                const float rC = 1.f / (1.f + __expf(-(crS + br0)));
                const float gC = 1.f / (1.f + __expf(-(cgS + br1)));
                const float bC = 1.f / (1.f + __expf(-(cbS + br2)));

                // ---- compositing over this wave's 16 samples (carry=0, exact) ----
                const float sdelta = sigma * STEPf;
                float scan = sdelta;
                #pragma unroll
                for (int off = 1; off < 16; off <<= 1) {
                    const float n = __shfl_up(scan, off);
                    if (lh >= off) scan += n;
                }
                const float T     = __expf(-(scan - sdelta));
                const float alpha = 1.f - __expf(-sdelta);
                const float w = T * alpha;
                aW  = w;
                aWT = w * tS;
                aR  = w * rC;
                aG  = w * gC;
                aB  = w * bC;
                Ssum = __shfl(scan, (lane & 48) | 15);   // tile total (per g-group)

                // ---- reduce over the 16 lh lanes ----
                #pragma unroll
                for (int off = 1; off < 16; off <<= 1) {
                    aW  += __shfl_xor(aW,  off);
                    aWT += __shfl_xor(aWT, off);
                    aR  += __shfl_xor(aR,  off);
                    aG  += __shfl_xor(aG,  off);
                    aB  += __shfl_xor(aB,  off);
                }
            }
        }

        if (lane == 0) {
            sRed[par][wid][0] = aW;  sRed[par][wid][1] = aWT; sRed[par][wid][2] = aR;
            sRed[par][wid][3] = aG;  sRed[par][wid][4] = aB;  sRed[par][wid][5] = Ssum;
        }
        __syncthreads();
        if (tid == 0) {
            // combine 8 tile-partials in sample order (wid order), exact factoring
            float f = 1.f, W = 0.f, WT = 0.f, R = 0.f, G = 0.f, B = 0.f;
            #pragma unroll
            for (int i = 0; i < 8; ++i) {
                W  += f * sRed[par][i][0];
                WT += f * sRed[par][i][1];
                R  += f * sRed[par][i][2];
                G  += f * sRed[par][i][3];
                B  += f * sRed[par][i][4];
                f  *= __expf(-sRed[par][i][5]);
            }
            const float bg_ = 1.f - W;
            out[ray * 3 + 0] = R + bg_;
            out[ray * 3 + 1] = G + bg_;
            out[ray * 3 + 2] = B + bg_;
            out[3 * nrays + ray] = WT;
            out[4 * nrays + ray] = W;
        }
        // no trailing barrier: next iteration uses sRed[par^1]; sPdB is same-wave
    }
}

extern "C" void kernel_launch(void* const* d_in, const int* in_sizes, int n_in,
                              void* d_out, int out_size, void* d_ws, size_t ws_size,
                              hipStream_t stream) {
    const float* rays_o   = (const float*)d_in[0];
    const float* viewdirs = (const float*)d_in[1];
    const void*  occ      = (const void*) d_in[2];
    const float* W1 = (const float*)d_in[3];
    const float* b1 = (const float*)d_in[4];
    const float* W2 = (const float*)d_in[5];
    const float* b2 = (const float*)d_in[6];
    const float* Ws = (const float*)d_in[7];
    const float* bs = (const float*)d_in[8];
    const float* Wc = (const float*)d_in[9];
    const float* Wd = (const float*)d_in[10];
    const float* bc = (const float*)d_in[11];
    const float* Wr = (const float*)d_in[12];
    const float* br = (const float*)d_in[13];
    float* out = (float*)d_out;

    const int nrays = in_sizes[0] / 3;
    int nblocks = 1024;                      // persistent: 4x512-thread blocks/CU
    if (nrays < nblocks) nblocks = nrays;    // 1 ray per block-iteration

    nerf_mfma<<<nblocks, 512, 0, stream>>>(rays_o, viewdirs, occ,
                                           W1, b1, W2, b2, Ws, bs, Wc, Wd, bc, Wr, br,
                                           out, nrays);
}

// Round 12
// 58.158 us; speedup vs baseline: 1.4358x; 1.1762x over previous
//
#include <hip/hip_runtime.h>
#include <math.h>

// NeRF fused volume renderer, MI355X (gfx950) — MFMA, 8-wave-per-ray.
// Round 12: r11 (clean 64-VGPR, wave = 16-sample tile) + pipelined shared setup.
//   r11 counter read: VALUBusy 40% dominated by 8x-duplicated per-ray setup
//   (AABB 6 divides + dir-posenc 6 sincos + 15-dot vs global Wd, ~200 ops/wave).
//   Fix: wave 7 computes the NEXT ray's setup into parity-buffered LDS
//   (sSet[2][8] scalars + sPdB[2][64] dir-feature vector) right before the
//   existing per-iteration barrier; all waves read it next iteration.
//   ~7/8 of setup VALU eliminated; no new barriers; VGPR shape unchanged.
//   Compositing factors exactly per 16-sample tile: P = sum_i (prod_{j<i} e^-Sj) Pi.
// Layouts (m89-verified / ISA doc): C/D col=lane&15, row=(lane>>4)*4+reg;
// x32 A/B k=(lane>>4)*8+e; x16 A/B k=(lane>>4)*4+e.

typedef _Float16 f16x8 __attribute__((ext_vector_type(8)));
typedef _Float16 f16x4 __attribute__((ext_vector_type(4)));
typedef float f32x4 __attribute__((ext_vector_type(4)));

static constexpr float STEPf = 0.040594940802395566f; // 3*sqrt(3)/128 in f32

static __device__ __forceinline__ unsigned pk2(float a, float b) {
    return __builtin_bit_cast(unsigned, __builtin_amdgcn_cvt_pkrtz(a, b));
}
static __device__ __forceinline__ f16x8 mk8(unsigned a, unsigned b, unsigned c, unsigned d) {
    uint4 u = make_uint4(a, b, c, d);
    return __builtin_bit_cast(f16x8, u);
}
static __device__ __forceinline__ f16x4 pkh(const f32x4 c) {
    uint2 u;
    u.x = pk2(fmaxf(c[0], 0.f), fmaxf(c[1], 0.f));
    u.y = pk2(fmaxf(c[2], 0.f), fmaxf(c[3], 0.f));
    return __builtin_bit_cast(f16x4, u);
}

extern "C" __global__ void __launch_bounds__(512)
nerf_mfma(const float* __restrict__ rays_o, const float* __restrict__ viewdirs,
          const void* __restrict__ occ,
          const float* __restrict__ W1g, const float* __restrict__ b1g,
          const float* __restrict__ W2g, const float* __restrict__ b2g,
          const float* __restrict__ Wsg, const float* __restrict__ bsg,
          const float* __restrict__ Wcg, const float* __restrict__ Wdg,
          const float* __restrict__ bcg, const float* __restrict__ Wrg,
          const float* __restrict__ brg,
          float* __restrict__ out, int nrays)
{
    __shared__ __align__(16) unsigned char sW1[64 * 64];
    __shared__ __align__(16) unsigned char sW2[64 * 128];
    __shared__ __align__(16) unsigned char sWc[64 * 128];
    __shared__ __align__(16) unsigned char sHC[16 * 128];
    __shared__ __align__(16) float sWs[64];
    __shared__ __align__(16) float sB1[64], sB2[64];
    __shared__ __align__(16) float sPdB[2][64];    // parity: (pe_d@Wd + bc) for cur/next ray
    __shared__ __align__(16) float sSet[2][8];     // parity: {ox,oy,oz,dx,dy,dz,t_near,t_far}
    __shared__ __align__(16) float sRed[2][8][6];  // parity x wave x {aW,aWT,aR,aG,aB,S}
    __shared__ int sKind;

    const int tid = threadIdx.x;   // 0..511
    const int lane = tid & 63;
    const int wid  = tid >> 6;     // 0..7

    // per-ray setup into parity slot p (executed by one wave, all lanes redundant)
    auto setupRay = [&](int r, int p) {
        const float ox = rays_o[r * 3 + 0], oy = rays_o[r * 3 + 1], oz = rays_o[r * 3 + 2];
        const float dxv = viewdirs[r * 3 + 0], dyv = viewdirs[r * 3 + 1], dzv = viewdirs[r * 3 + 2];
        const float sdx = fabsf(dxv) < 1e-8f ? 1e-8f : dxv;
        const float sdy = fabsf(dyv) < 1e-8f ? 1e-8f : dyv;
        const float sdz = fabsf(dzv) < 1e-8f ? 1e-8f : dzv;
        const float t1x = (-1.5f - ox) / sdx, t2x = (1.5f - ox) / sdx;
        const float t1y = (-1.5f - oy) / sdy, t2y = (1.5f - oy) / sdy;
        const float t1z = (-1.5f - oz) / sdz, t2z = (1.5f - oz) / sdz;
        const float tn = fmaxf(fmaxf(fminf(t1x, t2x), fminf(t1y, t2y)),
                               fmaxf(fminf(t1z, t2z), 0.f));
        const float tf = fminf(fminf(fmaxf(t1x, t2x), fmaxf(t1y, t2y)), fmaxf(t1z, t2z));
        // dir posenc dot Wd (lane j computes feature j)
        float ped[15];
        ped[0] = dxv; ped[1] = dyv; ped[2] = dzv;
        const float dc[3] = {dxv, dyv, dzv};
        #pragma unroll
        for (int c = 0; c < 3; ++c) {
            float s1, c1;
            __sincosf(dc[c], &s1, &c1);
            ped[3 + c * 4 + 0] = s1;
            ped[3 + c * 4 + 1] = 2.f * s1 * c1;
            ped[3 + c * 4 + 2] = c1;
            ped[3 + c * 4 + 3] = 1.f - 2.f * s1 * s1;
        }
        float pd = 0.f;
        #pragma unroll
        for (int i = 0; i < 15; ++i) pd += ped[i] * Wdg[i * 64 + lane];
        sPdB[p][lane] = pd + bcg[lane];
        if (lane == 0) {
            sSet[p][0] = ox;  sSet[p][1] = oy;  sSet[p][2] = oz;
            sSet[p][3] = dxv; sSet[p][4] = dyv; sSet[p][5] = dzv;
            sSet[p][6] = tn;  sSet[p][7] = tf;
        }
    };

    // ---------------- staging: COALESCED global reads, swizzled LDS writes ----
    for (int idx = tid; idx < 1024; idx += 512)             // zero sW1 (covers k-pad)
        ((uint32_t*)sW1)[idx] = 0u;
    __syncthreads();                                        // pad-zero before scatter
    for (int idx = tid; idx < 27 * 64; idx += 512) {        // W1, linear in memory
        const int k = idx >> 6, h = idx & 63;
        *(_Float16*)(sW1 + h * 64 + (((k >> 3) ^ (h & 3)) << 4) + ((k & 7) << 1)) =
            (_Float16)W1g[idx];
    }
    for (int idx = tid; idx < 64 * 64; idx += 512) {        // W2, Wc, linear
        const int k = idx >> 6, h = idx & 63;
        const int off = h * 128 + ((((k >> 2) ^ ((h & 7) << 1)) << 3)) + ((k & 3) << 1);
        *(_Float16*)(sW2 + off) = (_Float16)W2g[idx];
        *(_Float16*)(sWc + off) = (_Float16)Wcg[idx];
    }
    for (int idx = tid; idx < 192; idx += 512) {            // rgb head rows, linear
        const int kk = idx / 3, c = idx - 3 * kk;
        const _Float16 v = (_Float16)Wrg[idx];
        #pragma unroll
        for (int r = 0; r < 16; ++r) {
            if ((r % 3) == c) {
                const int off = r * 128 + ((((kk >> 2) ^ ((r & 7) << 1)) << 3)) + ((kk & 3) << 1);
                *(_Float16*)(sHC + off) = v;
            }
        }
    }
    if (tid < 64) {
        sB1[tid] = b1g[tid]; sB2[tid] = b2g[tid];
        sWs[tid] = Wsg[tid];
    }
    if (tid == 0) {   // sniff occ dtype: 0=u8, 1=i32, 2=f32
        const int*   oi = (const int*)occ;
        const float* of = (const float*)occ;
        bool i32ok = true, f32ok = true;
        for (int k = 0; k < 64; ++k) {
            if (oi[k] != 0 && oi[k] != 1) i32ok = false;
            const float f = of[k];
            if (!(f == 0.f || f == 1.f)) f32ok = false;
        }
        sKind = i32ok ? 1 : (f32ok ? 2 : 0);
    }
    if (wid == 7 && (int)blockIdx.x < nrays)                // prologue: setup ray0 -> par 0
        setupRay((int)blockIdx.x, 0);
    __syncthreads();

    const int bat  = wid >> 2;        // batch 0/1
    const int nt   = wid & 3;         // column tile within batch
    const int kind = sKind;
    const int lh = lane & 15, g = lane >> 4;
    const int swz8 = (lh & 7) << 1;

    const float bsV = bsg[0];
    const float br0 = brg[0], br1 = brg[1], br2 = brg[2];

    int par = 0;
    for (int ray = (int)blockIdx.x; ray < nrays; ray += (int)gridDim.x, par ^= 1) {

        // ---- read shared per-ray setup (LDS broadcast) ----
        const float ox = sSet[par][0], oy = sSet[par][1], oz = sSet[par][2];
        const float dxv = sSet[par][3], dyv = sSet[par][4], dzv = sSet[par][5];
        const float t_near = sSet[par][6], t_far = sSet[par][7];

        float aW = 0.f, aWT = 0.f, aR = 0.f, aG = 0.f, aB = 0.f, Ssum = 0.f;

        // own sample: s = 64*bat + 16*nt + lh  (wid-ordered contiguous 16-ranges)
        const float tS = t_near + ((float)((bat << 6) | (nt << 4) | lh) + 0.5f) * STEPf;
        const bool in_seg = tS < t_far;

        if (__ballot(in_seg) != 0ULL) {
            // ---- own-sample validity (occ gather) ----
            bool valid;
            {
                const float px = ox + dxv * tS, py = oy + dyv * tS, pz = oz + dzv * tS;
                const float cx = (px + 1.5f) * (128.f / 3.f);
                const float cy = (py + 1.5f) * (128.f / 3.f);
                const float cz = (pz + 1.5f) * (128.f / 3.f);
                const bool in_box = (cx >= 0.f) & (cx < 128.f) & (cy >= 0.f) & (cy < 128.f)
                                  & (cz >= 0.f) & (cz < 128.f);
                const int ix = min(max((int)floorf(cx), 0), 127);
                const int iy = min(max((int)floorf(cy), 0), 127);
                const int iz = min(max((int)floorf(cz), 0), 127);
                const int ci = (ix << 14) | (iy << 7) | iz;
                bool occv;
                if (kind == 1)      occv = ((const int*)occ)[ci] != 0;
                else if (kind == 2) occv = ((const float*)occ)[ci] != 0.f;
                else                occv = ((const unsigned char*)occ)[ci] != 0;
                valid = in_seg & in_box & occv;
            }

            if (__ballot(valid) != 0ULL) {
                // ---- posenc in x32-B layout: lane computes feats 8g..8g+7 of
                //      its own sample (col lh) ----
                f16x8 bx;
                {
                    const float qx = ox + dxv * tS, qy = oy + dyv * tS, qz = oz + dzv * tS;
                    const float u = (g < 2) ? qx : ((g == 2) ? qy : qz);
                    const float v = (g == 1) ? qy : ((g == 2) ? qz : 0.f);
                    float su1, cu1, sv1, cv1;
                    __sincosf(u, &su1, &cu1);
                    __sincosf(v, &sv1, &cv1);
                    const float su2 = 2.f * su1 * cu1, cu2 = 1.f - 2.f * su1 * su1;
                    const float su4 = 2.f * su2 * cu2, cu4 = 1.f - 2.f * su2 * su2;
                    const float su8 = 2.f * su4 * cu4, cu8 = 1.f - 2.f * su4 * su4;
                    const float sv2 = 2.f * sv1 * cv1, cv2 = 1.f - 2.f * sv1 * sv1;
                    const float sv4 = 2.f * sv2 * cv2, cv4 = 1.f - 2.f * sv2 * sv2;
                    const float sv8 = 2.f * sv4 * cv4;
                    const bool g0 = (g == 0);
                    const float f0 = g0 ? qx : cu2;
                    const float f1 = g0 ? qy : cu4;
                    const float f2 = g0 ? qz : cu8;
                    const float f3 = g0 ? su1 : sv1;
                    const float f4 = g0 ? su2 : sv2;
                    const float f5 = g0 ? su4 : sv4;
                    const float f6 = g0 ? su8 : sv8;
                    const float f7 = g0 ? cu1 : ((g == 3) ? 0.f : cv1);
                    bx = mk8(pk2(f0, f1), pk2(f2, f3), pk2(f4, f5), pk2(f6, f7));
                }

                // ---- L1 (16x16x32): bias as C ----
                f16x4 bh1[4];
                #pragma unroll
                for (int mt = 0; mt < 4; ++mt) {
                    const f32x4 bf = *(const f32x4*)&sB1[16 * mt + 4 * g];
                    const f16x8 a = *(const f16x8*)(sW1 + (16 * mt + lh) * 64 + ((g ^ (lh & 3)) << 4));
                    f32x4 c = __builtin_amdgcn_mfma_f32_16x16x32_f16(a, bx, bf, 0, 0, 0);
                    bh1[mt] = pkh(c);   // D rows 4g+r == B k 4g+e for k-step mt
                }
                // ---- L2 (4 x 16x16x16) + fused VALU sigma partial ----
                f16x4 bh2[4];
                float sp = 0.f;
                #pragma unroll
                for (int mt = 0; mt < 4; ++mt) {
                    const int row = (16 * mt + lh) * 128;
                    const f16x4 a0 = *(const f16x4*)(sW2 + row + (((0 + g) ^ swz8) << 3));
                    const f16x4 a1 = *(const f16x4*)(sW2 + row + (((4 + g) ^ swz8) << 3));
                    const f16x4 a2 = *(const f16x4*)(sW2 + row + (((8 + g) ^ swz8) << 3));
                    const f16x4 a3 = *(const f16x4*)(sW2 + row + (((12 + g) ^ swz8) << 3));
                    const f32x4 bf = *(const f32x4*)&sB2[16 * mt + 4 * g];
                    const f32x4 ws = *(const f32x4*)&sWs[16 * mt + 4 * g];
                    f32x4 c = __builtin_amdgcn_mfma_f32_16x16x16f16(a0, bh1[0], bf, 0, 0, 0);
                    c = __builtin_amdgcn_mfma_f32_16x16x16f16(a1, bh1[1], c, 0, 0, 0);
                    c = __builtin_amdgcn_mfma_f32_16x16x16f16(a2, bh1[2], c, 0, 0, 0);
                    c = __builtin_amdgcn_mfma_f32_16x16x16f16(a3, bh1[3], c, 0, 0, 0);
                    const float r0 = fmaxf(c[0], 0.f), r1 = fmaxf(c[1], 0.f);
                    const float r2 = fmaxf(c[2], 0.f), r3 = fmaxf(c[3], 0.f);
                    sp += ws[0] * r0 + ws[1] * r1 + ws[2] * r2 + ws[3] * r3;
                    uint2 u; u.x = pk2(r0, r1); u.y = pk2(r2, r3);
                    bh2[mt] = __builtin_bit_cast(f16x4, u);
                }
                // ---- Wc layer (C = pd + bc) + FUSED rgb head ----
                f32x4 accC;
                #pragma unroll
                for (int mt = 0; mt < 4; ++mt) {
                    const int row = (16 * mt + lh) * 128;
                    const f16x4 a0 = *(const f16x4*)(sWc + row + (((0 + g) ^ swz8) << 3));
                    const f16x4 a1 = *(const f16x4*)(sWc + row + (((4 + g) ^ swz8) << 3));
                    const f16x4 a2 = *(const f16x4*)(sWc + row + (((8 + g) ^ swz8) << 3));
                    const f16x4 a3 = *(const f16x4*)(sWc + row + (((12 + g) ^ swz8) << 3));
                    const f32x4 pdf = *(const f32x4*)&sPdB[par][16 * mt + 4 * g];
                    const f16x4 aC = *(const f16x4*)(sHC + lh * 128 + (((4 * mt + g) ^ swz8) << 3));
                    f32x4 c = __builtin_amdgcn_mfma_f32_16x16x16f16(a0, bh2[0], pdf, 0, 0, 0);
                    c = __builtin_amdgcn_mfma_f32_16x16x16f16(a1, bh2[1], c, 0, 0, 0);
                    c = __builtin_amdgcn_mfma_f32_16x16x16f16(a2, bh2[2], c, 0, 0, 0);
                    c = __builtin_amdgcn_mfma_f32_16x16x16f16(a3, bh2[3], c, 0, 0, 0);
                    const f16x4 bgf = pkh(c);
                    f32x4 ca = (mt == 0) ? f32x4{0.f, 0.f, 0.f, 0.f} : accC;
                    accC = __builtin_amdgcn_mfma_f32_16x16x16f16(aC, bgf, ca, 0, 0, 0);
                }
                // ---- sigma reduce over g-groups (all lanes get full sum) ----
                sp += __shfl_xor(sp, 16);
                sp += __shfl_xor(sp, 32);
                // ---- rgb extraction: row 4g+j has color (g+j)%3 -> j=(c-g) mod 3 ----
                const float crS = (g == 1) ? accC[2] : (g == 2) ? accC[1] : accC[0];
                const float cgS = (g == 0) ? accC[1] : (g == 1) ? accC[0]
                                : (g == 2) ? accC[2] : accC[1];
                const float cbS = (g == 0) ? accC[2] : (g == 1) ? accC[1]
                                : (g == 2) ? accC[0] : accC[2];

                const float sigma = valid ? fmaxf(sp + bsV, 0.f) : 0.f;
                const float rC = 1.f / (1.f + __expf(-(crS + br0)));
                const float gC = 1.f / (1.f + __expf(-(cgS + br1)));
                const float bC = 1.f / (1.f + __expf(-(cbS + br2)));

                // ---- compositing over this wave's 16 samples (carry=0, exact) ----
                const float sdelta = sigma * STEPf;
                float scan = sdelta;
                #pragma unroll
                for (int off = 1; off < 16; off <<= 1) {
                    const float n = __shfl_up(scan, off);
                    if (lh >= off) scan += n;
                }
                const float T     = __expf(-(scan - sdelta));
                const float alpha = 1.f - __expf(-sdelta);
                const float w = T * alpha;
                aW  = w;
                aWT = w * tS;
                aR  = w * rC;
                aG  = w * gC;
                aB  = w * bC;
                Ssum = __shfl(scan, (lane & 48) | 15);   // tile total (per g-group)

                // ---- reduce over the 16 lh lanes ----
                #pragma unroll
                for (int off = 1; off < 16; off <<= 1) {
                    aW  += __shfl_xor(aW,  off);
                    aWT += __shfl_xor(aWT, off);
                    aR  += __shfl_xor(aR,  off);
                    aG  += __shfl_xor(aG,  off);
                    aB  += __shfl_xor(aB,  off);
                }
            }
        }

        if (lane == 0) {
            sRed[par][wid][0] = aW;  sRed[par][wid][1] = aWT; sRed[par][wid][2] = aR;
            sRed[par][wid][3] = aG;  sRed[par][wid][4] = aB;  sRed[par][wid][5] = Ssum;
        }
        // ---- wave 7: prefetch next ray's setup into the other parity slot ----
        if (wid == 7) {
            const int nray = ray + (int)gridDim.x;
            if (nray < nrays) setupRay(nray, par ^ 1);
        }
        __syncthreads();
        if (tid == 0) {
            // combine 8 tile-partials in sample order (wid order), exact factoring
            float f = 1.f, W = 0.f, WT = 0.f, R = 0.f, G = 0.f, B = 0.f;
            #pragma unroll
            for (int i = 0; i < 8; ++i) {
                W  += f * sRed[par][i][0];
                WT += f * sRed[par][i][1];
                R  += f * sRed[par][i][2];
                G  += f * sRed[par][i][3];
                B  += f * sRed[par][i][4];
                f  *= __expf(-sRed[par][i][5]);
            }
            const float bg_ = 1.f - W;
            out[ray * 3 + 0] = R + bg_;
            out[ray * 3 + 1] = G + bg_;
            out[ray * 3 + 2] = B + bg_;
            out[3 * nrays + ray] = WT;
            out[4 * nrays + ray] = W;
        }
        // no trailing barrier: next iteration uses sRed/sSet/sPdB[par^1], which
        // were written before this barrier; sRed[par^1] is rewritten only after
        // the NEXT barrier.
    }
}

extern "C" void kernel_launch(void* const* d_in, const int* in_sizes, int n_in,
                              void* d_out, int out_size, void* d_ws, size_t ws_size,
                              hipStream_t stream) {
    const float* rays_o   = (const float*)d_in[0];
    const float* viewdirs = (const float*)d_in[1];
    const void*  occ      = (const void*) d_in[2];
    const float* W1 = (const float*)d_in[3];
    const float* b1 = (const float*)d_in[4];
    const float* W2 = (const float*)d_in[5];
    const float* b2 = (const float*)d_in[6];
    const float* Ws = (const float*)d_in[7];
    const float* bs = (const float*)d_in[8];
    const float* Wc = (const float*)d_in[9];
    const float* Wd = (const float*)d_in[10];
    const float* bc = (const float*)d_in[11];
    const float* Wr = (const float*)d_in[12];
    const float* br = (const float*)d_in[13];
    float* out = (float*)d_out;

    const int nrays = in_sizes[0] / 3;
    int nblocks = 1024;                      // persistent: 4x512-thread blocks/CU
    if (nrays < nblocks) nblocks = nrays;    // 1 ray per block-iteration

    nerf_mfma<<<nblocks, 512, 0, stream>>>(rays_o, viewdirs, occ,
                                           W1, b1, W2, b2, Ws, bs, Wc, Wd, bc, Wr, br,
                                           out, nrays);
}

// Round 13
// 51.215 us; speedup vs baseline: 1.6304x; 1.1355x over previous
//
#include <hip/hip_runtime.h>
#include <math.h>

// NeRF fused volume renderer, MI355X (gfx950) — MFMA, independent-wave design.
// Round 13: wave = WHOLE RAY, walking its 8x 16-sample tiles SEQUENTIALLY.
//   Tile factoring P = sum_i (prod_{j<i} e^-Sj) P_i carried in 6 registers
//   (f, W, WT, R, G, B) -> no inter-wave communication at all:
//     * zero barriers in the ray loop (only the one staging barrier)
//     * sRed / tid0-combine / wave7-setup all deleted
//     * 20-shuffle reduce per TILE -> per RAY (7 shuffles/tile remain)
//     * f < 6e-6 transmittance early-exit returns (free since independent)
//   Block = 256 thr = 4 independent waves; grid 1024 = 4 blocks/CU resident,
//   2 rays/wave, balanced, no tail. Natural VGPR allocation (no bounds games).
// Layouts (m89-verified / ISA doc): C/D col=lane&15, row=(lane>>4)*4+reg;
// x32 A/B k=(lane>>4)*8+e; x16 A/B k=(lane>>4)*4+e.

typedef _Float16 f16x8 __attribute__((ext_vector_type(8)));
typedef _Float16 f16x4 __attribute__((ext_vector_type(4)));
typedef float f32x4 __attribute__((ext_vector_type(4)));

static constexpr float STEPf = 0.040594940802395566f; // 3*sqrt(3)/128 in f32

static __device__ __forceinline__ unsigned pk2(float a, float b) {
    return __builtin_bit_cast(unsigned, __builtin_amdgcn_cvt_pkrtz(a, b));
}
static __device__ __forceinline__ f16x8 mk8(unsigned a, unsigned b, unsigned c, unsigned d) {
    uint4 u = make_uint4(a, b, c, d);
    return __builtin_bit_cast(f16x8, u);
}
static __device__ __forceinline__ f16x4 pkh(const f32x4 c) {
    uint2 u;
    u.x = pk2(fmaxf(c[0], 0.f), fmaxf(c[1], 0.f));
    u.y = pk2(fmaxf(c[2], 0.f), fmaxf(c[3], 0.f));
    return __builtin_bit_cast(f16x4, u);
}

extern "C" __global__ void __launch_bounds__(256)
nerf_mfma(const float* __restrict__ rays_o, const float* __restrict__ viewdirs,
          const void* __restrict__ occ,
          const float* __restrict__ W1g, const float* __restrict__ b1g,
          const float* __restrict__ W2g, const float* __restrict__ b2g,
          const float* __restrict__ Wsg, const float* __restrict__ bsg,
          const float* __restrict__ Wcg, const float* __restrict__ Wdg,
          const float* __restrict__ bcg, const float* __restrict__ Wrg,
          const float* __restrict__ brg,
          float* __restrict__ out, int nrays)
{
    __shared__ __align__(16) unsigned char sW1[64 * 64];
    __shared__ __align__(16) unsigned char sW2[64 * 128];
    __shared__ __align__(16) unsigned char sWc[64 * 128];
    __shared__ __align__(16) unsigned char sHC[16 * 128];
    __shared__ __align__(16) float sWs[64];
    __shared__ __align__(16) float sB1[64], sB2[64];
    __shared__ __align__(16) float sPdB[4][64];    // per-wave (pe_d@Wd + bc); same-wave RW
    __shared__ int sKind;

    const int tid = threadIdx.x;   // 0..255

    // ---------------- staging: COALESCED global reads, swizzled LDS writes ----
    for (int idx = tid; idx < 1024; idx += 256)             // zero sW1 (covers k-pad)
        ((uint32_t*)sW1)[idx] = 0u;
    __syncthreads();                                        // pad-zero before scatter
    for (int idx = tid; idx < 27 * 64; idx += 256) {        // W1, linear in memory
        const int k = idx >> 6, h = idx & 63;
        *(_Float16*)(sW1 + h * 64 + (((k >> 3) ^ (h & 3)) << 4) + ((k & 7) << 1)) =
            (_Float16)W1g[idx];
    }
    for (int idx = tid; idx < 64 * 64; idx += 256) {        // W2, Wc, linear
        const int k = idx >> 6, h = idx & 63;
        const int off = h * 128 + ((((k >> 2) ^ ((h & 7) << 1)) << 3)) + ((k & 3) << 1);
        *(_Float16*)(sW2 + off) = (_Float16)W2g[idx];
        *(_Float16*)(sWc + off) = (_Float16)Wcg[idx];
    }
    for (int idx = tid; idx < 192; idx += 256) {            // rgb head rows, linear
        const int kk = idx / 3, c = idx - 3 * kk;
        const _Float16 v = (_Float16)Wrg[idx];
        #pragma unroll
        for (int r = 0; r < 16; ++r) {
            if ((r % 3) == c) {
                const int off = r * 128 + ((((kk >> 2) ^ ((r & 7) << 1)) << 3)) + ((kk & 3) << 1);
                *(_Float16*)(sHC + off) = v;
            }
        }
    }
    if (tid < 64) {
        sB1[tid] = b1g[tid]; sB2[tid] = b2g[tid];
        sWs[tid] = Wsg[tid];
    }
    if (tid == 0) {   // sniff occ dtype: 0=u8, 1=i32, 2=f32
        const int*   oi = (const int*)occ;
        const float* of = (const float*)occ;
        bool i32ok = true, f32ok = true;
        for (int k = 0; k < 64; ++k) {
            if (oi[k] != 0 && oi[k] != 1) i32ok = false;
            const float f = of[k];
            if (!(f == 0.f || f == 1.f)) f32ok = false;
        }
        sKind = i32ok ? 1 : (f32ok ? 2 : 0);
    }
    __syncthreads();   // the ONLY block-wide barrier

    const int lane = tid & 63;
    const int wid  = tid >> 6;        // 0..3: wave = independent ray stream
    const int kind = sKind;
    const int lh = lane & 15, g = lane >> 4;
    const int swz8 = (lh & 7) << 1;

    const float bsV = bsg[0];
    const float br0 = brg[0], br1 = brg[1], br2 = brg[2];

    const int rayStride = (int)(gridDim.x << 2);
    for (int ray = (int)(blockIdx.x << 2) + wid; ray < nrays; ray += rayStride) {

        // ---- per-ray setup (this wave only; no sharing, no barrier) ----
        const float ox = rays_o[ray * 3 + 0], oy = rays_o[ray * 3 + 1], oz = rays_o[ray * 3 + 2];
        const float dxv = viewdirs[ray * 3 + 0], dyv = viewdirs[ray * 3 + 1], dzv = viewdirs[ray * 3 + 2];
        const float sdx = fabsf(dxv) < 1e-8f ? 1e-8f : dxv;
        const float sdy = fabsf(dyv) < 1e-8f ? 1e-8f : dyv;
        const float sdz = fabsf(dzv) < 1e-8f ? 1e-8f : dzv;
        const float t1x = (-1.5f - ox) / sdx, t2x = (1.5f - ox) / sdx;
        const float t1y = (-1.5f - oy) / sdy, t2y = (1.5f - oy) / sdy;
        const float t1z = (-1.5f - oz) / sdz, t2z = (1.5f - oz) / sdz;
        const float t_near = fmaxf(fmaxf(fminf(t1x, t2x), fminf(t1y, t2y)),
                                   fmaxf(fminf(t1z, t2z), 0.f));
        const float t_far  = fminf(fminf(fmaxf(t1x, t2x), fmaxf(t1y, t2y)), fmaxf(t1z, t2z));

        float W = 0.f, WT = 0.f, Rr = 0.f, Gg = 0.f, Bb = 0.f;

        if (t_near < t_far) {
            // dir posenc -> sPdB[wid] (lane j computes feature j; same-wave RW)
            {
                float ped[15];
                ped[0] = dxv; ped[1] = dyv; ped[2] = dzv;
                const float dc[3] = {dxv, dyv, dzv};
                #pragma unroll
                for (int c = 0; c < 3; ++c) {
                    float s1, c1;
                    __sincosf(dc[c], &s1, &c1);
                    ped[3 + c * 4 + 0] = s1;
                    ped[3 + c * 4 + 1] = 2.f * s1 * c1;
                    ped[3 + c * 4 + 2] = c1;
                    ped[3 + c * 4 + 3] = 1.f - 2.f * s1 * s1;
                }
                float pd = 0.f;
                #pragma unroll
                for (int i = 0; i < 15; ++i) pd += ped[i] * Wdg[i * 64 + lane];
                sPdB[wid][lane] = pd + bcg[lane];
            }

            float f = 1.f;
            #pragma unroll 1
            for (int bt = 0; bt < 8; ++bt) {
                const float tS = t_near + ((float)((bt << 4) | lh) + 0.5f) * STEPf;
                const bool in_seg = tS < t_far;
                if (__ballot(in_seg) == 0ULL) break;   // tiles ascend in t: done

                // ---- own-sample validity (occ gather) ----
                bool valid;
                {
                    const float px = ox + dxv * tS, py = oy + dyv * tS, pz = oz + dzv * tS;
                    const float cx = (px + 1.5f) * (128.f / 3.f);
                    const float cy = (py + 1.5f) * (128.f / 3.f);
                    const float cz = (pz + 1.5f) * (128.f / 3.f);
                    const bool in_box = (cx >= 0.f) & (cx < 128.f) & (cy >= 0.f) & (cy < 128.f)
                                      & (cz >= 0.f) & (cz < 128.f);
                    const int ix = min(max((int)floorf(cx), 0), 127);
                    const int iy = min(max((int)floorf(cy), 0), 127);
                    const int iz = min(max((int)floorf(cz), 0), 127);
                    const int ci = (ix << 14) | (iy << 7) | iz;
                    bool occv;
                    if (kind == 1)      occv = ((const int*)occ)[ci] != 0;
                    else if (kind == 2) occv = ((const float*)occ)[ci] != 0.f;
                    else                occv = ((const unsigned char*)occ)[ci] != 0;
                    valid = in_seg & in_box & occv;
                }
                if (__ballot(valid) == 0ULL) continue;  // empty tile: S_tile = 0, f unchanged

                // ---- posenc in x32-B layout: lane -> feats 8g..8g+7 of sample lh ----
                f16x8 bx;
                {
                    const float qx = ox + dxv * tS, qy = oy + dyv * tS, qz = oz + dzv * tS;
                    const float u = (g < 2) ? qx : ((g == 2) ? qy : qz);
                    const float v = (g == 1) ? qy : ((g == 2) ? qz : 0.f);
                    float su1, cu1, sv1, cv1;
                    __sincosf(u, &su1, &cu1);
                    __sincosf(v, &sv1, &cv1);
                    const float su2 = 2.f * su1 * cu1, cu2 = 1.f - 2.f * su1 * su1;
                    const float su4 = 2.f * su2 * cu2, cu4 = 1.f - 2.f * su2 * su2;
                    const float su8 = 2.f * su4 * cu4, cu8 = 1.f - 2.f * su4 * su4;
                    const float sv2 = 2.f * sv1 * cv1, cv2 = 1.f - 2.f * sv1 * sv1;
                    const float sv4 = 2.f * sv2 * cv2, cv4 = 1.f - 2.f * sv2 * sv2;
                    const float sv8 = 2.f * sv4 * cv4;
                    const bool g0 = (g == 0);
                    const float f0 = g0 ? qx : cu2;
                    const float f1 = g0 ? qy : cu4;
                    const float f2 = g0 ? qz : cu8;
                    const float f3 = g0 ? su1 : sv1;
                    const float f4 = g0 ? su2 : sv2;
                    const float f5 = g0 ? su4 : sv4;
                    const float f6 = g0 ? su8 : sv8;
                    const float f7 = g0 ? cu1 : ((g == 3) ? 0.f : cv1);
                    bx = mk8(pk2(f0, f1), pk2(f2, f3), pk2(f4, f5), pk2(f6, f7));
                }

                // ---- L1 (16x16x32): bias as C ----
                f16x4 bh1[4];
                #pragma unroll
                for (int mt = 0; mt < 4; ++mt) {
                    const f32x4 bf = *(const f32x4*)&sB1[16 * mt + 4 * g];
                    const f16x8 a = *(const f16x8*)(sW1 + (16 * mt + lh) * 64 + ((g ^ (lh & 3)) << 4));
                    f32x4 c = __builtin_amdgcn_mfma_f32_16x16x32_f16(a, bx, bf, 0, 0, 0);
                    bh1[mt] = pkh(c);   // D rows 4g+r == B k 4g+e for k-step mt
                }
                // ---- L2 (4 x 16x16x16) + fused VALU sigma partial ----
                f16x4 bh2[4];
                float sp = 0.f;
                #pragma unroll
                for (int mt = 0; mt < 4; ++mt) {
                    const int row = (16 * mt + lh) * 128;
                    const f16x4 a0 = *(const f16x4*)(sW2 + row + (((0 + g) ^ swz8) << 3));
                    const f16x4 a1 = *(const f16x4*)(sW2 + row + (((4 + g) ^ swz8) << 3));
                    const f16x4 a2 = *(const f16x4*)(sW2 + row + (((8 + g) ^ swz8) << 3));
                    const f16x4 a3 = *(const f16x4*)(sW2 + row + (((12 + g) ^ swz8) << 3));
                    const f32x4 bf = *(const f32x4*)&sB2[16 * mt + 4 * g];
                    const f32x4 ws = *(const f32x4*)&sWs[16 * mt + 4 * g];
                    f32x4 c = __builtin_amdgcn_mfma_f32_16x16x16f16(a0, bh1[0], bf, 0, 0, 0);
                    c = __builtin_amdgcn_mfma_f32_16x16x16f16(a1, bh1[1], c, 0, 0, 0);
                    c = __builtin_amdgcn_mfma_f32_16x16x16f16(a2, bh1[2], c, 0, 0, 0);
                    c = __builtin_amdgcn_mfma_f32_16x16x16f16(a3, bh1[3], c, 0, 0, 0);
                    const float r0 = fmaxf(c[0], 0.f), r1 = fmaxf(c[1], 0.f);
                    const float r2 = fmaxf(c[2], 0.f), r3 = fmaxf(c[3], 0.f);
                    sp += ws[0] * r0 + ws[1] * r1 + ws[2] * r2 + ws[3] * r3;
                    uint2 u; u.x = pk2(r0, r1); u.y = pk2(r2, r3);
                    bh2[mt] = __builtin_bit_cast(f16x4, u);
                }
                // ---- Wc layer (C = pd + bc) + FUSED rgb head ----
                f32x4 accC;
                #pragma unroll
                for (int mt = 0; mt < 4; ++mt) {
                    const int row = (16 * mt + lh) * 128;
                    const f16x4 a0 = *(const f16x4*)(sWc + row + (((0 + g) ^ swz8) << 3));
                    const f16x4 a1 = *(const f16x4*)(sWc + row + (((4 + g) ^ swz8) << 3));
                    const f16x4 a2 = *(const f16x4*)(sWc + row + (((8 + g) ^ swz8) << 3));
                    const f16x4 a3 = *(const f16x4*)(sWc + row + (((12 + g) ^ swz8) << 3));
                    const f32x4 pdf = *(const f32x4*)&sPdB[wid][16 * mt + 4 * g];
                    const f16x4 aC = *(const f16x4*)(sHC + lh * 128 + (((4 * mt + g) ^ swz8) << 3));
                    f32x4 c = __builtin_amdgcn_mfma_f32_16x16x16f16(a0, bh2[0], pdf, 0, 0, 0);
                    c = __builtin_amdgcn_mfma_f32_16x16x16f16(a1, bh2[1], c, 0, 0, 0);
                    c = __builtin_amdgcn_mfma_f32_16x16x16f16(a2, bh2[2], c, 0, 0, 0);
                    c = __builtin_amdgcn_mfma_f32_16x16x16f16(a3, bh2[3], c, 0, 0, 0);
                    const f16x4 bgf = pkh(c);
                    f32x4 ca = (mt == 0) ? f32x4{0.f, 0.f, 0.f, 0.f} : accC;
                    accC = __builtin_amdgcn_mfma_f32_16x16x16f16(aC, bgf, ca, 0, 0, 0);
                }
                // ---- sigma reduce over g-groups (all lanes get full sum) ----
                sp += __shfl_xor(sp, 16);
                sp += __shfl_xor(sp, 32);
                // ---- rgb extraction: row 4g+j has color (g+j)%3 ----
                const float crS = (g == 1) ? accC[2] : (g == 2) ? accC[1] : accC[0];
                const float cgS = (g == 0) ? accC[1] : (g == 1) ? accC[0]
                                : (g == 2) ? accC[2] : accC[1];
                const float cbS = (g == 0) ? accC[2] : (g == 1) ? accC[1]
                                : (g == 2) ? accC[0] : accC[2];

                const float sigma = valid ? fmaxf(sp + bsV, 0.f) : 0.f;
                const float rC = 1.f / (1.f + __expf(-(crS + br0)));
                const float gC = 1.f / (1.f + __expf(-(cgS + br1)));
                const float bC = 1.f / (1.f + __expf(-(cbS + br2)));

                // ---- compositing over this tile (carry via f, exact) ----
                const float sdelta = sigma * STEPf;
                float scan = sdelta;
                #pragma unroll
                for (int off = 1; off < 16; off <<= 1) {
                    const float n = __shfl_up(scan, off);
                    if (lh >= off) scan += n;
                }
                const float T     = __expf(-(scan - sdelta));
                const float alpha = 1.f - __expf(-sdelta);
                const float w = f * T * alpha;          // tile factor folded per-lane
                W  += w;
                WT += w * tS;
                Rr += w * rC;
                Gg += w * gC;
                Bb += w * bC;
                const float Stile = __shfl(scan, (lane & 48) | 15);  // tile sigma-sum
                f *= __expf(-Stile);
                if (f < 6e-6f) break;                   // transmittance exhausted
            }
        }

        // ---- ONE reduce over the 16 lh lanes per ray (values g-replicated) ----
        #pragma unroll
        for (int off = 1; off < 16; off <<= 1) {
            W  += __shfl_xor(W,  off);
            WT += __shfl_xor(WT, off);
            Rr += __shfl_xor(Rr, off);
            Gg += __shfl_xor(Gg, off);
            Bb += __shfl_xor(Bb, off);
        }
        if (lane == 0) {
            const float bg_ = 1.f - W;
            out[ray * 3 + 0] = Rr + bg_;
            out[ray * 3 + 1] = Gg + bg_;
            out[ray * 3 + 2] = Bb + bg_;
            out[3 * nrays + ray] = WT;
            out[4 * nrays + ray] = W;
        }
    }
}

extern "C" void kernel_launch(void* const* d_in, const int* in_sizes, int n_in,
                              void* d_out, int out_size, void* d_ws, size_t ws_size,
                              hipStream_t stream) {
    const float* rays_o   = (const float*)d_in[0];
    const float* viewdirs = (const float*)d_in[1];
    const void*  occ      = (const void*) d_in[2];
    const float* W1 = (const float*)d_in[3];
    const float* b1 = (const float*)d_in[4];
    const float* W2 = (const float*)d_in[5];
    const float* b2 = (const float*)d_in[6];
    const float* Ws = (const float*)d_in[7];
    const float* bs = (const float*)d_in[8];
    const float* Wc = (const float*)d_in[9];
    const float* Wd = (const float*)d_in[10];
    const float* bc = (const float*)d_in[11];
    const float* Wr = (const float*)d_in[12];
    const float* br = (const float*)d_in[13];
    float* out = (float*)d_out;

    const int nrays = in_sizes[0] / 3;
    int nblocks = 1024;                      // 4 blocks/CU resident, 2 rays/wave, balanced
    const int needed = (nrays + 3) / 4;      // 4 independent rays (waves) per block
    if (needed < nblocks) nblocks = needed;

    nerf_mfma<<<nblocks, 256, 0, stream>>>(rays_o, viewdirs, occ,
                                           W1, b1, W2, b2, Ws, bs, Wc, Wd, bc, Wr, br,
                                           out, nrays);
}

// Round 15
// 51.083 us; speedup vs baseline: 1.6347x; 1.0026x over previous
//
#include <hip/hip_runtime.h>
#include <math.h>

// NeRF fused volume renderer, MI355X (gfx950) — MFMA, independent-wave design.
// Round 15: r13 (51.2us, proven) + occ-gather software pipeline + setprio.
//   * r14's work-stealing hung (atomic queue in d_ws without ws_size check) —
//     reverted; no atomics, no d_ws use. r13's stride-4096 ray interleave keeps
//     load balance adequate.
//   * Occ-gather pipeline: tile bt+1's {t,inseg,inbox,raw occupancy word} is
//     computed right after bt's validity is consumed -> the L2 gather retires
//     under bt's ~1000cy MLP (1 exposed gather per ray instead of 8).
//   * s_setprio(1) around MFMA chains (T5): waves here are independent and
//     phase-skewed (attn-like regime, +4-7% m191), not lockstep (m190 null).
//   * Everything else = r13: wave = whole ray, 8x16-sample tiles sequential,
//     6-register carry (f,W,WT,R,G,B), zero main-loop barriers.
// Layouts (m89-verified / ISA doc): C/D col=lane&15, row=(lane>>4)*4+reg;
// x32 A/B k=(lane>>4)*8+e; x16 A/B k=(lane>>4)*4+e.

typedef _Float16 f16x8 __attribute__((ext_vector_type(8)));
typedef _Float16 f16x4 __attribute__((ext_vector_type(4)));
typedef float f32x4 __attribute__((ext_vector_type(4)));

static constexpr float STEPf = 0.040594940802395566f; // 3*sqrt(3)/128 in f32

static __device__ __forceinline__ unsigned pk2(float a, float b) {
    return __builtin_bit_cast(unsigned, __builtin_amdgcn_cvt_pkrtz(a, b));
}
static __device__ __forceinline__ f16x8 mk8(unsigned a, unsigned b, unsigned c, unsigned d) {
    uint4 u = make_uint4(a, b, c, d);
    return __builtin_bit_cast(f16x8, u);
}
static __device__ __forceinline__ f16x4 pkh(const f32x4 c) {
    uint2 u;
    u.x = pk2(fmaxf(c[0], 0.f), fmaxf(c[1], 0.f));
    u.y = pk2(fmaxf(c[2], 0.f), fmaxf(c[3], 0.f));
    return __builtin_bit_cast(f16x4, u);
}

extern "C" __global__ void __launch_bounds__(256)
nerf_mfma(const float* __restrict__ rays_o, const float* __restrict__ viewdirs,
          const void* __restrict__ occ,
          const float* __restrict__ W1g, const float* __restrict__ b1g,
          const float* __restrict__ W2g, const float* __restrict__ b2g,
          const float* __restrict__ Wsg, const float* __restrict__ bsg,
          const float* __restrict__ Wcg, const float* __restrict__ Wdg,
          const float* __restrict__ bcg, const float* __restrict__ Wrg,
          const float* __restrict__ brg,
          float* __restrict__ out, int nrays)
{
    __shared__ __align__(16) unsigned char sW1[64 * 64];
    __shared__ __align__(16) unsigned char sW2[64 * 128];
    __shared__ __align__(16) unsigned char sWc[64 * 128];
    __shared__ __align__(16) unsigned char sHC[16 * 128];
    __shared__ __align__(16) float sWs[64];
    __shared__ __align__(16) float sB1[64], sB2[64];
    __shared__ __align__(16) float sPdB[4][64];    // per-wave (pe_d@Wd + bc); same-wave RW
    __shared__ int sKind;

    const int tid = threadIdx.x;   // 0..255

    // ---------------- staging: COALESCED global reads, swizzled LDS writes ----
    for (int idx = tid; idx < 1024; idx += 256)             // zero sW1 (covers k-pad)
        ((uint32_t*)sW1)[idx] = 0u;
    __syncthreads();                                        // pad-zero before scatter
    for (int idx = tid; idx < 27 * 64; idx += 256) {        // W1, linear in memory
        const int k = idx >> 6, h = idx & 63;
        *(_Float16*)(sW1 + h * 64 + (((k >> 3) ^ (h & 3)) << 4) + ((k & 7) << 1)) =
            (_Float16)W1g[idx];
    }
    for (int idx = tid; idx < 64 * 64; idx += 256) {        // W2, Wc, linear
        const int k = idx >> 6, h = idx & 63;
        const int off = h * 128 + ((((k >> 2) ^ ((h & 7) << 1)) << 3)) + ((k & 3) << 1);
        *(_Float16*)(sW2 + off) = (_Float16)W2g[idx];
        *(_Float16*)(sWc + off) = (_Float16)Wcg[idx];
    }
    for (int idx = tid; idx < 192; idx += 256) {            // rgb head rows, linear
        const int kk = idx / 3, c = idx - 3 * kk;
        const _Float16 v = (_Float16)Wrg[idx];
        #pragma unroll
        for (int r = 0; r < 16; ++r) {
            if ((r % 3) == c) {
                const int off = r * 128 + ((((kk >> 2) ^ ((r & 7) << 1)) << 3)) + ((kk & 3) << 1);
                *(_Float16*)(sHC + off) = v;
            }
        }
    }
    if (tid < 64) {
        sB1[tid] = b1g[tid]; sB2[tid] = b2g[tid];
        sWs[tid] = Wsg[tid];
    }
    if (tid == 0) {   // sniff occ dtype: 0=u8, else 32-bit raw (i32/f32 both !=0 test)
        const int*   oi = (const int*)occ;
        const float* of = (const float*)occ;
        bool i32ok = true, f32ok = true;
        for (int k = 0; k < 64; ++k) {
            if (oi[k] != 0 && oi[k] != 1) i32ok = false;
            const float f = of[k];
            if (!(f == 0.f || f == 1.f)) f32ok = false;
        }
        sKind = (i32ok || f32ok) ? 1 : 0;
    }
    __syncthreads();   // the ONLY block-wide barrier

    const int lane = tid & 63;
    const int wid  = tid >> 6;        // 0..3: wave = independent ray stream
    const int kind = sKind;
    const int lh = lane & 15, g = lane >> 4;
    const int swz8 = (lh & 7) << 1;

    const float bsV = bsg[0];
    const float br0 = brg[0], br1 = brg[1], br2 = brg[2];

    const int rayStride = (int)(gridDim.x << 2);
    for (int ray = (int)(blockIdx.x << 2) + wid; ray < nrays; ray += rayStride) {

        // ---- per-ray setup (this wave only; no sharing, no barrier) ----
        const float ox = rays_o[ray * 3 + 0], oy = rays_o[ray * 3 + 1], oz = rays_o[ray * 3 + 2];
        const float dxv = viewdirs[ray * 3 + 0], dyv = viewdirs[ray * 3 + 1], dzv = viewdirs[ray * 3 + 2];
        const float sdx = fabsf(dxv) < 1e-8f ? 1e-8f : dxv;
        const float sdy = fabsf(dyv) < 1e-8f ? 1e-8f : dyv;
        const float sdz = fabsf(dzv) < 1e-8f ? 1e-8f : dzv;
        const float t1x = (-1.5f - ox) / sdx, t2x = (1.5f - ox) / sdx;
        const float t1y = (-1.5f - oy) / sdy, t2y = (1.5f - oy) / sdy;
        const float t1z = (-1.5f - oz) / sdz, t2z = (1.5f - oz) / sdz;
        const float t_near = fmaxf(fmaxf(fminf(t1x, t2x), fminf(t1y, t2y)),
                                   fmaxf(fminf(t1z, t2z), 0.f));
        const float t_far  = fminf(fminf(fmaxf(t1x, t2x), fmaxf(t1y, t2y)), fmaxf(t1z, t2z));

        float W = 0.f, WT = 0.f, Rr = 0.f, Gg = 0.f, Bb = 0.f;

        if (t_near < t_far) {
            // dir posenc -> sPdB[wid] (lane j computes feature j; same-wave RW)
            {
                float ped[15];
                ped[0] = dxv; ped[1] = dyv; ped[2] = dzv;
                const float dc[3] = {dxv, dyv, dzv};
                #pragma unroll
                for (int c = 0; c < 3; ++c) {
                    float s1, c1;
                    __sincosf(dc[c], &s1, &c1);
                    ped[3 + c * 4 + 0] = s1;
                    ped[3 + c * 4 + 1] = 2.f * s1 * c1;
                    ped[3 + c * 4 + 2] = c1;
                    ped[3 + c * 4 + 3] = 1.f - 2.f * s1 * s1;
                }
                float pd = 0.f;
                #pragma unroll
                for (int i = 0; i < 15; ++i) pd += ped[i] * Wdg[i * 64 + lane];
                sPdB[wid][lane] = pd + bcg[lane];
            }

            // tile validity precompute: {t, inseg, inbox, raw occupancy word}
            auto prepTile = [&](int bt, float& tSo, bool& insego, bool& inboxo, unsigned& rawo) {
                const float t = t_near + ((float)((bt << 4) | lh) + 0.5f) * STEPf;
                tSo = t;
                insego = t < t_far;
                const float px = ox + dxv * t, py = oy + dyv * t, pz = oz + dzv * t;
                const float cx = (px + 1.5f) * (128.f / 3.f);
                const float cy = (py + 1.5f) * (128.f / 3.f);
                const float cz = (pz + 1.5f) * (128.f / 3.f);
                inboxo = (cx >= 0.f) & (cx < 128.f) & (cy >= 0.f) & (cy < 128.f)
                       & (cz >= 0.f) & (cz < 128.f);
                const int ix = min(max((int)floorf(cx), 0), 127);
                const int iy = min(max((int)floorf(cy), 0), 127);
                const int iz = min(max((int)floorf(cz), 0), 127);
                const int ci = (ix << 14) | (iy << 7) | iz;
                rawo = (kind == 0) ? (unsigned)((const unsigned char*)occ)[ci]
                                   : ((const unsigned*)occ)[ci];
            };

            float tS_c; bool inseg_c, inbox_c; unsigned raw_c;
            prepTile(0, tS_c, inseg_c, inbox_c, raw_c);

            float f = 1.f;
            #pragma unroll 1
            for (int bt = 0; bt < 8; ++bt) {
                if (__ballot(inseg_c) == 0ULL) break;   // tiles ascend in t: done

                // prefetch next tile's validity (gather hidden under this tile's MLP)
                float tS_n = 0.f; bool inseg_n = false, inbox_n = false; unsigned raw_n = 0u;
                if (bt < 7) prepTile(bt + 1, tS_n, inseg_n, inbox_n, raw_n);

                const bool valid = inseg_c & inbox_c & (raw_c != 0u);
                const float tS = tS_c;

                if (__ballot(valid) != 0ULL) {
                    // ---- posenc in x32-B layout: lane -> feats 8g..8g+7 of sample lh ----
                    f16x8 bx;
                    {
                        const float qx = ox + dxv * tS, qy = oy + dyv * tS, qz = oz + dzv * tS;
                        const float u = (g < 2) ? qx : ((g == 2) ? qy : qz);
                        const float v = (g == 1) ? qy : ((g == 2) ? qz : 0.f);
                        float su1, cu1, sv1, cv1;
                        __sincosf(u, &su1, &cu1);
                        __sincosf(v, &sv1, &cv1);
                        const float su2 = 2.f * su1 * cu1, cu2 = 1.f - 2.f * su1 * su1;
                        const float su4 = 2.f * su2 * cu2, cu4 = 1.f - 2.f * su2 * su2;
                        const float su8 = 2.f * su4 * cu4, cu8 = 1.f - 2.f * su4 * su4;
                        const float sv2 = 2.f * sv1 * cv1, cv2 = 1.f - 2.f * sv1 * sv1;
                        const float sv4 = 2.f * sv2 * cv2, cv4 = 1.f - 2.f * sv2 * sv2;
                        const float sv8 = 2.f * sv4 * cv4;
                        const bool g0 = (g == 0);
                        const float f0 = g0 ? qx : cu2;
                        const float f1 = g0 ? qy : cu4;
                        const float f2 = g0 ? qz : cu8;
                        const float f3 = g0 ? su1 : sv1;
                        const float f4 = g0 ? su2 : sv2;
                        const float f5 = g0 ? su4 : sv4;
                        const float f6 = g0 ? su8 : sv8;
                        const float f7 = g0 ? cu1 : ((g == 3) ? 0.f : cv1);
                        bx = mk8(pk2(f0, f1), pk2(f2, f3), pk2(f4, f5), pk2(f6, f7));
                    }

                    // ---- L1 (16x16x32): bias as C ----
                    __builtin_amdgcn_s_setprio(1);
                    f16x4 bh1[4];
                    #pragma unroll
                    for (int mt = 0; mt < 4; ++mt) {
                        const f32x4 bf = *(const f32x4*)&sB1[16 * mt + 4 * g];
                        const f16x8 a = *(const f16x8*)(sW1 + (16 * mt + lh) * 64 + ((g ^ (lh & 3)) << 4));
                        f32x4 c = __builtin_amdgcn_mfma_f32_16x16x32_f16(a, bx, bf, 0, 0, 0);
                        bh1[mt] = pkh(c);   // D rows 4g+r == B k 4g+e for k-step mt
                    }
                    // ---- L2 (4 x 16x16x16) + fused VALU sigma partial ----
                    f16x4 bh2[4];
                    float sp = 0.f;
                    #pragma unroll
                    for (int mt = 0; mt < 4; ++mt) {
                        const int row = (16 * mt + lh) * 128;
                        const f16x4 a0 = *(const f16x4*)(sW2 + row + (((0 + g) ^ swz8) << 3));
                        const f16x4 a1 = *(const f16x4*)(sW2 + row + (((4 + g) ^ swz8) << 3));
                        const f16x4 a2 = *(const f16x4*)(sW2 + row + (((8 + g) ^ swz8) << 3));
                        const f16x4 a3 = *(const f16x4*)(sW2 + row + (((12 + g) ^ swz8) << 3));
                        const f32x4 bf = *(const f32x4*)&sB2[16 * mt + 4 * g];
                        const f32x4 ws = *(const f32x4*)&sWs[16 * mt + 4 * g];
                        f32x4 c = __builtin_amdgcn_mfma_f32_16x16x16f16(a0, bh1[0], bf, 0, 0, 0);
                        c = __builtin_amdgcn_mfma_f32_16x16x16f16(a1, bh1[1], c, 0, 0, 0);
                        c = __builtin_amdgcn_mfma_f32_16x16x16f16(a2, bh1[2], c, 0, 0, 0);
                        c = __builtin_amdgcn_mfma_f32_16x16x16f16(a3, bh1[3], c, 0, 0, 0);
                        const float r0 = fmaxf(c[0], 0.f), r1 = fmaxf(c[1], 0.f);
                        const float r2 = fmaxf(c[2], 0.f), r3 = fmaxf(c[3], 0.f);
                        sp += ws[0] * r0 + ws[1] * r1 + ws[2] * r2 + ws[3] * r3;
                        uint2 u; u.x = pk2(r0, r1); u.y = pk2(r2, r3);
                        bh2[mt] = __builtin_bit_cast(f16x4, u);
                    }
                    // ---- Wc layer (C = pd + bc) + FUSED rgb head ----
                    f32x4 accC;
                    #pragma unroll
                    for (int mt = 0; mt < 4; ++mt) {
                        const int row = (16 * mt + lh) * 128;
                        const f16x4 a0 = *(const f16x4*)(sWc + row + (((0 + g) ^ swz8) << 3));
                        const f16x4 a1 = *(const f16x4*)(sWc + row + (((4 + g) ^ swz8) << 3));
                        const f16x4 a2 = *(const f16x4*)(sWc + row + (((8 + g) ^ swz8) << 3));
                        const f16x4 a3 = *(const f16x4*)(sWc + row + (((12 + g) ^ swz8) << 3));
                        const f32x4 pdf = *(const f32x4*)&sPdB[wid][16 * mt + 4 * g];
                        const f16x4 aC = *(const f16x4*)(sHC + lh * 128 + (((4 * mt + g) ^ swz8) << 3));
                        f32x4 c = __builtin_amdgcn_mfma_f32_16x16x16f16(a0, bh2[0], pdf, 0, 0, 0);
                        c = __builtin_amdgcn_mfma_f32_16x16x16f16(a1, bh2[1], c, 0, 0, 0);
                        c = __builtin_amdgcn_mfma_f32_16x16x16f16(a2, bh2[2], c, 0, 0, 0);
                        c = __builtin_amdgcn_mfma_f32_16x16x16f16(a3, bh2[3], c, 0, 0, 0);
                        const f16x4 bgf = pkh(c);
                        f32x4 ca = (mt == 0) ? f32x4{0.f, 0.f, 0.f, 0.f} : accC;
                        accC = __builtin_amdgcn_mfma_f32_16x16x16f16(aC, bgf, ca, 0, 0, 0);
                    }
                    __builtin_amdgcn_s_setprio(0);
                    // ---- sigma reduce over g-groups (all lanes get full sum) ----
                    sp += __shfl_xor(sp, 16);
                    sp += __shfl_xor(sp, 32);
                    // ---- rgb extraction: row 4g+j has color (g+j)%3 ----
                    const float crS = (g == 1) ? accC[2] : (g == 2) ? accC[1] : accC[0];
                    const float cgS = (g == 0) ? accC[1] : (g == 1) ? accC[0]
                                    : (g == 2) ? accC[2] : accC[1];
                    const float cbS = (g == 0) ? accC[2] : (g == 1) ? accC[1]
                                    : (g == 2) ? accC[0] : accC[2];

                    const float sigma = valid ? fmaxf(sp + bsV, 0.f) : 0.f;
                    const float rC = 1.f / (1.f + __expf(-(crS + br0)));
                    const float gC = 1.f / (1.f + __expf(-(cgS + br1)));
                    const float bC = 1.f / (1.f + __expf(-(cbS + br2)));

                    // ---- compositing over this tile (carry via f, exact) ----
                    const float sdelta = sigma * STEPf;
                    float scan = sdelta;
                    #pragma unroll
                    for (int off = 1; off < 16; off <<= 1) {
                        const float n = __shfl_up(scan, off);
                        if (lh >= off) scan += n;
                    }
                    const float T     = __expf(-(scan - sdelta));
                    const float alpha = 1.f - __expf(-sdelta);
                    const float w = f * T * alpha;          // tile factor folded per-lane
                    W  += w;
                    WT += w * tS;
                    Rr += w * rC;
                    Gg += w * gC;
                    Bb += w * bC;
                    const float Stile = __shfl(scan, (lane & 48) | 15);  // tile sigma-sum
                    f *= __expf(-Stile);
                }

                tS_c = tS_n; inseg_c = inseg_n; inbox_c = inbox_n; raw_c = raw_n;
                if (f < 6e-6f) break;                   // transmittance exhausted
            }
        }

        // ---- ONE reduce over the 16 lh lanes per ray (values g-replicated) ----
        #pragma unroll
        for (int off = 1; off < 16; off <<= 1) {
            W  += __shfl_xor(W,  off);
            WT += __shfl_xor(WT, off);
            Rr += __shfl_xor(Rr, off);
            Gg += __shfl_xor(Gg, off);
            Bb += __shfl_xor(Bb, off);
        }
        if (lane == 0) {
            const float bg_ = 1.f - W;
            out[ray * 3 + 0] = Rr + bg_;
            out[ray * 3 + 1] = Gg + bg_;
            out[ray * 3 + 2] = Bb + bg_;
            out[3 * nrays + ray] = WT;
            out[4 * nrays + ray] = W;
        }
    }
}

extern "C" void kernel_launch(void* const* d_in, const int* in_sizes, int n_in,
                              void* d_out, int out_size, void* d_ws, size_t ws_size,
                              hipStream_t stream) {
    const float* rays_o   = (const float*)d_in[0];
    const float* viewdirs = (const float*)d_in[1];
    const void*  occ      = (const void*) d_in[2];
    const float* W1 = (const float*)d_in[3];
    const float* b1 = (const float*)d_in[4];
    const float* W2 = (const float*)d_in[5];
    const float* b2 = (const float*)d_in[6];
    const float* Ws = (const float*)d_in[7];
    const float* bs = (const float*)d_in[8];
    const float* Wc = (const float*)d_in[9];
    const float* Wd = (const float*)d_in[10];
    const float* bc = (const float*)d_in[11];
    const float* Wr = (const float*)d_in[12];
    const float* br = (const float*)d_in[13];
    float* out = (float*)d_out;

    const int nrays = in_sizes[0] / 3;
    int nblocks = 1024;                      // 4 blocks/CU resident (16-waves/CU tier)
    const int needed = (nrays + 3) / 4;      // 4 independent rays (waves) per block
    if (needed < nblocks) nblocks = needed;

    nerf_mfma<<<nblocks, 256, 0, stream>>>(rays_o, viewdirs, occ,
                                           W1, b1, W2, b2, Ws, bs, Wc, Wd, bc, Wr, br,
                                           out, nrays);
}

// Round 16
// 46.387 us; speedup vs baseline: 1.8001x; 1.1012x over previous
//
#include <hip/hip_runtime.h>
#include <math.h>

// NeRF fused volume renderer, MI355X (gfx950) — MFMA, independent-wave design.
// Round 16: r13 structure at the 64-VGPR occupancy tier (32 waves/CU).
//   * r15 lesson: VGPR=76 pins residency at 4 waves/SIMD (16 waves/CU); the
//     gather-pipeline + setprio were null -> dropped (saves their registers).
//   * __launch_bounds__(512, 8): cap = exactly the 64-VGPR tier (true peak live
//     ~55-60, so expect ~no spill; WRITE_SIZE is the tell — r8/r10 caps at
//     128/85 were NOT tiers and triggered tier-jump spills).
//   * 512-thread blocks, 8 waves = 8 independent rays; grid 1024 = 8192/8 =
//     exactly 4 blocks/CU x 256 CU: whole grid co-resident at 32 waves/CU.
//     Per-CU work = sum of its 32 rays -> tight cross-CU variance.
//   * Everything else = r13: wave = whole ray, 8x16-sample tiles sequential,
//     6-register carry (f,W,WT,R,G,B), zero main-loop barriers.
// Layouts (m89-verified / ISA doc): C/D col=lane&15, row=(lane>>4)*4+reg;
// x32 A/B k=(lane>>4)*8+e; x16 A/B k=(lane>>4)*4+e.

typedef _Float16 f16x8 __attribute__((ext_vector_type(8)));
typedef _Float16 f16x4 __attribute__((ext_vector_type(4)));
typedef float f32x4 __attribute__((ext_vector_type(4)));

static constexpr float STEPf = 0.040594940802395566f; // 3*sqrt(3)/128 in f32

static __device__ __forceinline__ unsigned pk2(float a, float b) {
    return __builtin_bit_cast(unsigned, __builtin_amdgcn_cvt_pkrtz(a, b));
}
static __device__ __forceinline__ f16x8 mk8(unsigned a, unsigned b, unsigned c, unsigned d) {
    uint4 u = make_uint4(a, b, c, d);
    return __builtin_bit_cast(f16x8, u);
}
static __device__ __forceinline__ f16x4 pkh(const f32x4 c) {
    uint2 u;
    u.x = pk2(fmaxf(c[0], 0.f), fmaxf(c[1], 0.f));
    u.y = pk2(fmaxf(c[2], 0.f), fmaxf(c[3], 0.f));
    return __builtin_bit_cast(f16x4, u);
}

extern "C" __global__ void __launch_bounds__(512, 8)
nerf_mfma(const float* __restrict__ rays_o, const float* __restrict__ viewdirs,
          const void* __restrict__ occ,
          const float* __restrict__ W1g, const float* __restrict__ b1g,
          const float* __restrict__ W2g, const float* __restrict__ b2g,
          const float* __restrict__ Wsg, const float* __restrict__ bsg,
          const float* __restrict__ Wcg, const float* __restrict__ Wdg,
          const float* __restrict__ bcg, const float* __restrict__ Wrg,
          const float* __restrict__ brg,
          float* __restrict__ out, int nrays)
{
    __shared__ __align__(16) unsigned char sW1[64 * 64];
    __shared__ __align__(16) unsigned char sW2[64 * 128];
    __shared__ __align__(16) unsigned char sWc[64 * 128];
    __shared__ __align__(16) unsigned char sHC[16 * 128];
    __shared__ __align__(16) float sWs[64];
    __shared__ __align__(16) float sB1[64], sB2[64];
    __shared__ __align__(16) float sPdB[8][64];    // per-wave (pe_d@Wd + bc); same-wave RW
    __shared__ int sKind;

    const int tid = threadIdx.x;   // 0..511

    // ---------------- staging: COALESCED global reads, swizzled LDS writes ----
    for (int idx = tid; idx < 1024; idx += 512)             // zero sW1 (covers k-pad)
        ((uint32_t*)sW1)[idx] = 0u;
    __syncthreads();                                        // pad-zero before scatter
    for (int idx = tid; idx < 27 * 64; idx += 512) {        // W1, linear in memory
        const int k = idx >> 6, h = idx & 63;
        *(_Float16*)(sW1 + h * 64 + (((k >> 3) ^ (h & 3)) << 4) + ((k & 7) << 1)) =
            (_Float16)W1g[idx];
    }
    for (int idx = tid; idx < 64 * 64; idx += 512) {        // W2, Wc, linear
        const int k = idx >> 6, h = idx & 63;
        const int off = h * 128 + ((((k >> 2) ^ ((h & 7) << 1)) << 3)) + ((k & 3) << 1);
        *(_Float16*)(sW2 + off) = (_Float16)W2g[idx];
        *(_Float16*)(sWc + off) = (_Float16)Wcg[idx];
    }
    for (int idx = tid; idx < 192; idx += 512) {            // rgb head rows, linear
        const int kk = idx / 3, c = idx - 3 * kk;
        const _Float16 v = (_Float16)Wrg[idx];
        #pragma unroll
        for (int r = 0; r < 16; ++r) {
            if ((r % 3) == c) {
                const int off = r * 128 + ((((kk >> 2) ^ ((r & 7) << 1)) << 3)) + ((kk & 3) << 1);
                *(_Float16*)(sHC + off) = v;
            }
        }
    }
    if (tid < 64) {
        sB1[tid] = b1g[tid]; sB2[tid] = b2g[tid];
        sWs[tid] = Wsg[tid];
    }
    if (tid == 0) {   // sniff occ dtype: 0=u8, else 32-bit raw (i32/f32 both !=0 test)
        const int*   oi = (const int*)occ;
        const float* of = (const float*)occ;
        bool i32ok = true, f32ok = true;
        for (int k = 0; k < 64; ++k) {
            if (oi[k] != 0 && oi[k] != 1) i32ok = false;
            const float f = of[k];
            if (!(f == 0.f || f == 1.f)) f32ok = false;
        }
        sKind = (i32ok || f32ok) ? 1 : 0;
    }
    __syncthreads();   // the ONLY block-wide barrier

    const int lane = tid & 63;
    const int wid  = tid >> 6;        // 0..7: wave = independent ray
    const int kind = sKind;
    const int lh = lane & 15, g = lane >> 4;
    const int swz8 = (lh & 7) << 1;

    const float bsV = bsg[0];
    const float br0 = brg[0], br1 = brg[1], br2 = brg[2];

    const int ray = (int)(blockIdx.x << 3) + wid;   // 1 ray per wave, whole grid resident
    if (ray >= nrays) return;

    // ---- per-ray setup (this wave only; no sharing, no barrier) ----
    const float ox = rays_o[ray * 3 + 0], oy = rays_o[ray * 3 + 1], oz = rays_o[ray * 3 + 2];
    const float dxv = viewdirs[ray * 3 + 0], dyv = viewdirs[ray * 3 + 1], dzv = viewdirs[ray * 3 + 2];
    const float sdx = fabsf(dxv) < 1e-8f ? 1e-8f : dxv;
    const float sdy = fabsf(dyv) < 1e-8f ? 1e-8f : dyv;
    const float sdz = fabsf(dzv) < 1e-8f ? 1e-8f : dzv;
    const float t1x = (-1.5f - ox) / sdx, t2x = (1.5f - ox) / sdx;
    const float t1y = (-1.5f - oy) / sdy, t2y = (1.5f - oy) / sdy;
    const float t1z = (-1.5f - oz) / sdz, t2z = (1.5f - oz) / sdz;
    const float t_near = fmaxf(fmaxf(fminf(t1x, t2x), fminf(t1y, t2y)),
                               fmaxf(fminf(t1z, t2z), 0.f));
    const float t_far  = fminf(fminf(fmaxf(t1x, t2x), fmaxf(t1y, t2y)), fmaxf(t1z, t2z));

    float W = 0.f, WT = 0.f, Rr = 0.f, Gg = 0.f, Bb = 0.f;

    if (t_near < t_far) {
        // dir posenc -> sPdB[wid] (lane j computes feature j; same-wave RW)
        {
            float ped[15];
            ped[0] = dxv; ped[1] = dyv; ped[2] = dzv;
            const float dc[3] = {dxv, dyv, dzv};
            #pragma unroll
            for (int c = 0; c < 3; ++c) {
                float s1, c1;
                __sincosf(dc[c], &s1, &c1);
                ped[3 + c * 4 + 0] = s1;
                ped[3 + c * 4 + 1] = 2.f * s1 * c1;
                ped[3 + c * 4 + 2] = c1;
                ped[3 + c * 4 + 3] = 1.f - 2.f * s1 * s1;
            }
            float pd = 0.f;
            #pragma unroll
            for (int i = 0; i < 15; ++i) pd += ped[i] * Wdg[i * 64 + lane];
            sPdB[wid][lane] = pd + bcg[lane];
        }

        float f = 1.f;
        #pragma unroll 1
        for (int bt = 0; bt < 8; ++bt) {
            const float tS = t_near + ((float)((bt << 4) | lh) + 0.5f) * STEPf;
            const bool in_seg = tS < t_far;
            if (__ballot(in_seg) == 0ULL) break;   // tiles ascend in t: done

            // ---- own-sample validity (occ gather) ----
            bool valid;
            {
                const float px = ox + dxv * tS, py = oy + dyv * tS, pz = oz + dzv * tS;
                const float cx = (px + 1.5f) * (128.f / 3.f);
                const float cy = (py + 1.5f) * (128.f / 3.f);
                const float cz = (pz + 1.5f) * (128.f / 3.f);
                const bool in_box = (cx >= 0.f) & (cx < 128.f) & (cy >= 0.f) & (cy < 128.f)
                                  & (cz >= 0.f) & (cz < 128.f);
                const int ix = min(max((int)floorf(cx), 0), 127);
                const int iy = min(max((int)floorf(cy), 0), 127);
                const int iz = min(max((int)floorf(cz), 0), 127);
                const int ci = (ix << 14) | (iy << 7) | iz;
                const unsigned raw = (kind == 0) ? (unsigned)((const unsigned char*)occ)[ci]
                                                 : ((const unsigned*)occ)[ci];
                valid = in_seg & in_box & (raw != 0u);
            }
            if (__ballot(valid) == 0ULL) continue;  // empty tile: S_tile = 0, f unchanged

            // ---- posenc in x32-B layout: lane -> feats 8g..8g+7 of sample lh ----
            f16x8 bx;
            {
                const float qx = ox + dxv * tS, qy = oy + dyv * tS, qz = oz + dzv * tS;
                const float u = (g < 2) ? qx : ((g == 2) ? qy : qz);
                const float v = (g == 1) ? qy : ((g == 2) ? qz : 0.f);
                float su1, cu1, sv1, cv1;
                __sincosf(u, &su1, &cu1);
                __sincosf(v, &sv1, &cv1);
                const float su2 = 2.f * su1 * cu1, cu2 = 1.f - 2.f * su1 * su1;
                const float su4 = 2.f * su2 * cu2, cu4 = 1.f - 2.f * su2 * su2;
                const float su8 = 2.f * su4 * cu4, cu8 = 1.f - 2.f * su4 * su4;
                const float sv2 = 2.f * sv1 * cv1, cv2 = 1.f - 2.f * sv1 * sv1;
                const float sv4 = 2.f * sv2 * cv2, cv4 = 1.f - 2.f * sv2 * sv2;
                const float sv8 = 2.f * sv4 * cv4;
                const bool g0 = (g == 0);
                const float f0 = g0 ? qx : cu2;
                const float f1 = g0 ? qy : cu4;
                const float f2 = g0 ? qz : cu8;
                const float f3 = g0 ? su1 : sv1;
                const float f4 = g0 ? su2 : sv2;
                const float f5 = g0 ? su4 : sv4;
                const float f6 = g0 ? su8 : sv8;
                const float f7 = g0 ? cu1 : ((g == 3) ? 0.f : cv1);
                bx = mk8(pk2(f0, f1), pk2(f2, f3), pk2(f4, f5), pk2(f6, f7));
            }

            // ---- L1 (16x16x32): bias as C ----
            f16x4 bh1[4];
            #pragma unroll
            for (int mt = 0; mt < 4; ++mt) {
                const f32x4 bf = *(const f32x4*)&sB1[16 * mt + 4 * g];
                const f16x8 a = *(const f16x8*)(sW1 + (16 * mt + lh) * 64 + ((g ^ (lh & 3)) << 4));
                f32x4 c = __builtin_amdgcn_mfma_f32_16x16x32_f16(a, bx, bf, 0, 0, 0);
                bh1[mt] = pkh(c);   // D rows 4g+r == B k 4g+e for k-step mt
            }
            // ---- L2 (4 x 16x16x16) + fused VALU sigma partial ----
            f16x4 bh2[4];
            float sp = 0.f;
            #pragma unroll
            for (int mt = 0; mt < 4; ++mt) {
                const int row = (16 * mt + lh) * 128;
                const f16x4 a0 = *(const f16x4*)(sW2 + row + (((0 + g) ^ swz8) << 3));
                const f16x4 a1 = *(const f16x4*)(sW2 + row + (((4 + g) ^ swz8) << 3));
                const f16x4 a2 = *(const f16x4*)(sW2 + row + (((8 + g) ^ swz8) << 3));
                const f16x4 a3 = *(const f16x4*)(sW2 + row + (((12 + g) ^ swz8) << 3));
                const f32x4 bf = *(const f32x4*)&sB2[16 * mt + 4 * g];
                const f32x4 ws = *(const f32x4*)&sWs[16 * mt + 4 * g];
                f32x4 c = __builtin_amdgcn_mfma_f32_16x16x16f16(a0, bh1[0], bf, 0, 0, 0);
                c = __builtin_amdgcn_mfma_f32_16x16x16f16(a1, bh1[1], c, 0, 0, 0);
                c = __builtin_amdgcn_mfma_f32_16x16x16f16(a2, bh1[2], c, 0, 0, 0);
                c = __builtin_amdgcn_mfma_f32_16x16x16f16(a3, bh1[3], c, 0, 0, 0);
                const float r0 = fmaxf(c[0], 0.f), r1 = fmaxf(c[1], 0.f);
                const float r2 = fmaxf(c[2], 0.f), r3 = fmaxf(c[3], 0.f);
                sp += ws[0] * r0 + ws[1] * r1 + ws[2] * r2 + ws[3] * r3;
                uint2 u; u.x = pk2(r0, r1); u.y = pk2(r2, r3);
                bh2[mt] = __builtin_bit_cast(f16x4, u);
            }
            // ---- Wc layer (C = pd + bc) + FUSED rgb head ----
            f32x4 accC;
            #pragma unroll
            for (int mt = 0; mt < 4; ++mt) {
                const int row = (16 * mt + lh) * 128;
                const f16x4 a0 = *(const f16x4*)(sWc + row + (((0 + g) ^ swz8) << 3));
                const f16x4 a1 = *(const f16x4*)(sWc + row + (((4 + g) ^ swz8) << 3));
                const f16x4 a2 = *(const f16x4*)(sWc + row + (((8 + g) ^ swz8) << 3));
                const f16x4 a3 = *(const f16x4*)(sWc + row + (((12 + g) ^ swz8) << 3));
                const f32x4 pdf = *(const f32x4*)&sPdB[wid][16 * mt + 4 * g];
                const f16x4 aC = *(const f16x4*)(sHC + lh * 128 + (((4 * mt + g) ^ swz8) << 3));
                f32x4 c = __builtin_amdgcn_mfma_f32_16x16x16f16(a0, bh2[0], pdf, 0, 0, 0);
                c = __builtin_amdgcn_mfma_f32_16x16x16f16(a1, bh2[1], c, 0, 0, 0);
                c = __builtin_amdgcn_mfma_f32_16x16x16f16(a2, bh2[2], c, 0, 0, 0);
                c = __builtin_amdgcn_mfma_f32_16x16x16f16(a3, bh2[3], c, 0, 0, 0);
                const f16x4 bgf = pkh(c);
                f32x4 ca = (mt == 0) ? f32x4{0.f, 0.f, 0.f, 0.f} : accC;
                accC = __builtin_amdgcn_mfma_f32_16x16x16f16(aC, bgf, ca, 0, 0, 0);
            }
            // ---- sigma reduce over g-groups (all lanes get full sum) ----
            sp += __shfl_xor(sp, 16);
            sp += __shfl_xor(sp, 32);
            // ---- rgb extraction: row 4g+j has color (g+j)%3 ----
            const float crS = (g == 1) ? accC[2] : (g == 2) ? accC[1] : accC[0];
            const float cgS = (g == 0) ? accC[1] : (g == 1) ? accC[0]
                            : (g == 2) ? accC[2] : accC[1];
            const float cbS = (g == 0) ? accC[2] : (g == 1) ? accC[1]
                            : (g == 2) ? accC[0] : accC[2];

            const float sigma = valid ? fmaxf(sp + bsV, 0.f) : 0.f;
            const float rC = 1.f / (1.f + __expf(-(crS + br0)));
            const float gC = 1.f / (1.f + __expf(-(cgS + br1)));
            const float bC = 1.f / (1.f + __expf(-(cbS + br2)));

            // ---- compositing over this tile (carry via f, exact) ----
            const float sdelta = sigma * STEPf;
            float scan = sdelta;
            #pragma unroll
            for (int off = 1; off < 16; off <<= 1) {
                const float n = __shfl_up(scan, off);
                if (lh >= off) scan += n;
            }
            const float T     = __expf(-(scan - sdelta));
            const float alpha = 1.f - __expf(-sdelta);
            const float w = f * T * alpha;          // tile factor folded per-lane
            W  += w;
            WT += w * tS;
            Rr += w * rC;
            Gg += w * gC;
            Bb += w * bC;
            const float Stile = __shfl(scan, (lane & 48) | 15);  // tile sigma-sum
            f *= __expf(-Stile);
            if (f < 6e-6f) break;                   // transmittance exhausted
        }
    }

    // ---- ONE reduce over the 16 lh lanes per ray (values g-replicated) ----
    #pragma unroll
    for (int off = 1; off < 16; off <<= 1) {
        W  += __shfl_xor(W,  off);
        WT += __shfl_xor(WT, off);
        Rr += __shfl_xor(Rr, off);
        Gg += __shfl_xor(Gg, off);
        Bb += __shfl_xor(Bb, off);
    }
    if (lane == 0) {
        const float bg_ = 1.f - W;
        out[ray * 3 + 0] = Rr + bg_;
        out[ray * 3 + 1] = Gg + bg_;
        out[ray * 3 + 2] = Bb + bg_;
        out[3 * nrays + ray] = WT;
        out[4 * nrays + ray] = W;
    }
}

extern "C" void kernel_launch(void* const* d_in, const int* in_sizes, int n_in,
                              void* d_out, int out_size, void* d_ws, size_t ws_size,
                              hipStream_t stream) {
    const float* rays_o   = (const float*)d_in[0];
    const float* viewdirs = (const float*)d_in[1];
    const void*  occ      = (const void*) d_in[2];
    const float* W1 = (const float*)d_in[3];
    const float* b1 = (const float*)d_in[4];
    const float* W2 = (const float*)d_in[5];
    const float* b2 = (const float*)d_in[6];
    const float* Ws = (const float*)d_in[7];
    const float* bs = (const float*)d_in[8];
    const float* Wc = (const float*)d_in[9];
    const float* Wd = (const float*)d_in[10];
    const float* bc = (const float*)d_in[11];
    const float* Wr = (const float*)d_in[12];
    const float* br = (const float*)d_in[13];
    float* out = (float*)d_out;

    const int nrays = in_sizes[0] / 3;
    const int nblocks = (nrays + 7) / 8;     // 8 rays (waves) per 512-thread block
                                             // nrays=8192 -> 1024 = whole grid resident

    nerf_mfma<<<nblocks, 512, 0, stream>>>(rays_o, viewdirs, occ,
                                           W1, b1, W2, b2, Ws, bs, Wc, Wd, bc, Wr, br,
                                           out, nrays);
}

// Round 17
// 42.584 us; speedup vs baseline: 1.9609x; 1.0893x over previous
//
#include <hip/hip_runtime.h>
#include <math.h>

// NeRF fused volume renderer, MI355X (gfx950) — MFMA, independent-wave design.
// Round 17: r16 (46.4us best) + wave-uniform scalarization to kill the spill.
//   r16 counters: launch_bounds(512,8) made the allocator land at VGPR=32 with
//   26.8MB/dispatch scratch (true peak live ~55-60; 64 would fit cleanly).
//   Fix: move the 8 loop-spanning wave-uniform scalars (o, d, t_near, t_far)
//   into SGPRs via readfirstlane (ray index -> scalar loads; computed t's ->
//   readfirstlane of the f32 bits). ~8 VGPRs of pressure removed -> allocator
//   should fit the 64 tier with no spill at the same 32 waves/CU occupancy.
//   Everything else = r16: 512-thr blocks, 8 waves = 8 independent rays, whole
//   grid resident; wave walks its ray's 8x16-sample tiles sequentially with
//   6-register carry (f,W,WT,R,G,B); zero main-loop barriers.
// Layouts (m89-verified / ISA doc): C/D col=lane&15, row=(lane>>4)*4+reg;
// x32 A/B k=(lane>>4)*8+e; x16 A/B k=(lane>>4)*4+e.

typedef _Float16 f16x8 __attribute__((ext_vector_type(8)));
typedef _Float16 f16x4 __attribute__((ext_vector_type(4)));
typedef float f32x4 __attribute__((ext_vector_type(4)));

static constexpr float STEPf = 0.040594940802395566f; // 3*sqrt(3)/128 in f32

static __device__ __forceinline__ unsigned pk2(float a, float b) {
    return __builtin_bit_cast(unsigned, __builtin_amdgcn_cvt_pkrtz(a, b));
}
static __device__ __forceinline__ f16x8 mk8(unsigned a, unsigned b, unsigned c, unsigned d) {
    uint4 u = make_uint4(a, b, c, d);
    return __builtin_bit_cast(f16x8, u);
}
static __device__ __forceinline__ f16x4 pkh(const f32x4 c) {
    uint2 u;
    u.x = pk2(fmaxf(c[0], 0.f), fmaxf(c[1], 0.f));
    u.y = pk2(fmaxf(c[2], 0.f), fmaxf(c[3], 0.f));
    return __builtin_bit_cast(f16x4, u);
}
// force a wave-uniform f32 into an SGPR
static __device__ __forceinline__ float rfl(float x) {
    return __builtin_bit_cast(float, __builtin_amdgcn_readfirstlane(__builtin_bit_cast(int, x)));
}

extern "C" __global__ void __launch_bounds__(512, 8)
nerf_mfma(const float* __restrict__ rays_o, const float* __restrict__ viewdirs,
          const void* __restrict__ occ,
          const float* __restrict__ W1g, const float* __restrict__ b1g,
          const float* __restrict__ W2g, const float* __restrict__ b2g,
          const float* __restrict__ Wsg, const float* __restrict__ bsg,
          const float* __restrict__ Wcg, const float* __restrict__ Wdg,
          const float* __restrict__ bcg, const float* __restrict__ Wrg,
          const float* __restrict__ brg,
          float* __restrict__ out, int nrays)
{
    __shared__ __align__(16) unsigned char sW1[64 * 64];
    __shared__ __align__(16) unsigned char sW2[64 * 128];
    __shared__ __align__(16) unsigned char sWc[64 * 128];
    __shared__ __align__(16) unsigned char sHC[16 * 128];
    __shared__ __align__(16) float sWs[64];
    __shared__ __align__(16) float sB1[64], sB2[64];
    __shared__ __align__(16) float sPdB[8][64];    // per-wave (pe_d@Wd + bc); same-wave RW
    __shared__ int sKind;

    const int tid = threadIdx.x;   // 0..511

    // ---------------- staging: COALESCED global reads, swizzled LDS writes ----
    for (int idx = tid; idx < 1024; idx += 512)             // zero sW1 (covers k-pad)
        ((uint32_t*)sW1)[idx] = 0u;
    __syncthreads();                                        // pad-zero before scatter
    for (int idx = tid; idx < 27 * 64; idx += 512) {        // W1, linear in memory
        const int k = idx >> 6, h = idx & 63;
        *(_Float16*)(sW1 + h * 64 + (((k >> 3) ^ (h & 3)) << 4) + ((k & 7) << 1)) =
            (_Float16)W1g[idx];
    }
    for (int idx = tid; idx < 64 * 64; idx += 512) {        // W2, Wc, linear
        const int k = idx >> 6, h = idx & 63;
        const int off = h * 128 + ((((k >> 2) ^ ((h & 7) << 1)) << 3)) + ((k & 3) << 1);
        *(_Float16*)(sW2 + off) = (_Float16)W2g[idx];
        *(_Float16*)(sWc + off) = (_Float16)Wcg[idx];
    }
    for (int idx = tid; idx < 192; idx += 512) {            // rgb head rows, linear
        const int kk = idx / 3, c = idx - 3 * kk;
        const _Float16 v = (_Float16)Wrg[idx];
        #pragma unroll
        for (int r = 0; r < 16; ++r) {
            if ((r % 3) == c) {
                const int off = r * 128 + ((((kk >> 2) ^ ((r & 7) << 1)) << 3)) + ((kk & 3) << 1);
                *(_Float16*)(sHC + off) = v;
            }
        }
    }
    if (tid < 64) {
        sB1[tid] = b1g[tid]; sB2[tid] = b2g[tid];
        sWs[tid] = Wsg[tid];
    }
    if (tid == 0) {   // sniff occ dtype: 0=u8, else 32-bit raw (i32/f32 both !=0 test)
        const int*   oi = (const int*)occ;
        const float* of = (const float*)occ;
        bool i32ok = true, f32ok = true;
        for (int k = 0; k < 64; ++k) {
            if (oi[k] != 0 && oi[k] != 1) i32ok = false;
            const float f = of[k];
            if (!(f == 0.f || f == 1.f)) f32ok = false;
        }
        sKind = (i32ok || f32ok) ? 1 : 0;
    }
    __syncthreads();   // the ONLY block-wide barrier

    const int lane = tid & 63;
    const int wid  = tid >> 6;        // 0..7: wave = independent ray
    const int kind = sKind;
    const int lh = lane & 15, g = lane >> 4;
    const int swz8 = (lh & 7) << 1;

    const float bsV = bsg[0];
    const float br0 = brg[0], br1 = brg[1], br2 = brg[2];

    const int ray = __builtin_amdgcn_readfirstlane((int)(blockIdx.x << 3) + wid);
    if (ray >= nrays) return;

    // ---- per-ray setup; uniform scalars end in SGPRs (scalar loads + rfl) ----
    const float ox = rays_o[ray * 3 + 0], oy = rays_o[ray * 3 + 1], oz = rays_o[ray * 3 + 2];
    const float dxv = viewdirs[ray * 3 + 0], dyv = viewdirs[ray * 3 + 1], dzv = viewdirs[ray * 3 + 2];
    float t_near, t_far;
    {
        const float sdx = fabsf(dxv) < 1e-8f ? 1e-8f : dxv;
        const float sdy = fabsf(dyv) < 1e-8f ? 1e-8f : dyv;
        const float sdz = fabsf(dzv) < 1e-8f ? 1e-8f : dzv;
        const float t1x = (-1.5f - ox) / sdx, t2x = (1.5f - ox) / sdx;
        const float t1y = (-1.5f - oy) / sdy, t2y = (1.5f - oy) / sdy;
        const float t1z = (-1.5f - oz) / sdz, t2z = (1.5f - oz) / sdz;
        t_near = rfl(fmaxf(fmaxf(fminf(t1x, t2x), fminf(t1y, t2y)),
                           fmaxf(fminf(t1z, t2z), 0.f)));
        t_far  = rfl(fminf(fminf(fmaxf(t1x, t2x), fmaxf(t1y, t2y)), fmaxf(t1z, t2z)));
    }

    float W = 0.f, WT = 0.f, Rr = 0.f, Gg = 0.f, Bb = 0.f;

    if (t_near < t_far) {
        // dir posenc -> sPdB[wid] (lane j computes feature j; same-wave RW)
        {
            float ped[15];
            ped[0] = dxv; ped[1] = dyv; ped[2] = dzv;
            const float dc[3] = {dxv, dyv, dzv};
            #pragma unroll
            for (int c = 0; c < 3; ++c) {
                float s1, c1;
                __sincosf(dc[c], &s1, &c1);
                ped[3 + c * 4 + 0] = s1;
                ped[3 + c * 4 + 1] = 2.f * s1 * c1;
                ped[3 + c * 4 + 2] = c1;
                ped[3 + c * 4 + 3] = 1.f - 2.f * s1 * s1;
            }
            float pd = 0.f;
            #pragma unroll
            for (int i = 0; i < 15; ++i) pd += ped[i] * Wdg[i * 64 + lane];
            sPdB[wid][lane] = pd + bcg[lane];
        }

        float f = 1.f;
        #pragma unroll 1
        for (int bt = 0; bt < 8; ++bt) {
            const float tS = t_near + ((float)((bt << 4) | lh) + 0.5f) * STEPf;
            const bool in_seg = tS < t_far;
            if (__ballot(in_seg) == 0ULL) break;   // tiles ascend in t: done

            // ---- own-sample validity (occ gather) ----
            bool valid;
            {
                const float px = ox + dxv * tS, py = oy + dyv * tS, pz = oz + dzv * tS;
                const float cx = (px + 1.5f) * (128.f / 3.f);
                const float cy = (py + 1.5f) * (128.f / 3.f);
                const float cz = (pz + 1.5f) * (128.f / 3.f);
                const bool in_box = (cx >= 0.f) & (cx < 128.f) & (cy >= 0.f) & (cy < 128.f)
                                  & (cz >= 0.f) & (cz < 128.f);
                const int ix = min(max((int)floorf(cx), 0), 127);
                const int iy = min(max((int)floorf(cy), 0), 127);
                const int iz = min(max((int)floorf(cz), 0), 127);
                const int ci = (ix << 14) | (iy << 7) | iz;
                const unsigned raw = (kind == 0) ? (unsigned)((const unsigned char*)occ)[ci]
                                                 : ((const unsigned*)occ)[ci];
                valid = in_seg & in_box & (raw != 0u);
            }
            if (__ballot(valid) == 0ULL) continue;  // empty tile: S_tile = 0, f unchanged

            // ---- posenc in x32-B layout: lane -> feats 8g..8g+7 of sample lh ----
            f16x8 bx;
            {
                const float qx = ox + dxv * tS, qy = oy + dyv * tS, qz = oz + dzv * tS;
                const float u = (g < 2) ? qx : ((g == 2) ? qy : qz);
                const float v = (g == 1) ? qy : ((g == 2) ? qz : 0.f);
                float su1, cu1, sv1, cv1;
                __sincosf(u, &su1, &cu1);
                __sincosf(v, &sv1, &cv1);
                const float su2 = 2.f * su1 * cu1, cu2 = 1.f - 2.f * su1 * su1;
                const float su4 = 2.f * su2 * cu2, cu4 = 1.f - 2.f * su2 * su2;
                const float su8 = 2.f * su4 * cu4, cu8 = 1.f - 2.f * su4 * su4;
                const float sv2 = 2.f * sv1 * cv1, cv2 = 1.f - 2.f * sv1 * sv1;
                const float sv4 = 2.f * sv2 * cv2, cv4 = 1.f - 2.f * sv2 * sv2;
                const float sv8 = 2.f * sv4 * cv4;
                const bool g0 = (g == 0);
                const float f0 = g0 ? qx : cu2;
                const float f1 = g0 ? qy : cu4;
                const float f2 = g0 ? qz : cu8;
                const float f3 = g0 ? su1 : sv1;
                const float f4 = g0 ? su2 : sv2;
                const float f5 = g0 ? su4 : sv4;
                const float f6 = g0 ? su8 : sv8;
                const float f7 = g0 ? cu1 : ((g == 3) ? 0.f : cv1);
                bx = mk8(pk2(f0, f1), pk2(f2, f3), pk2(f4, f5), pk2(f6, f7));
            }

            // ---- L1 (16x16x32): bias as C ----
            f16x4 bh1[4];
            #pragma unroll
            for (int mt = 0; mt < 4; ++mt) {
                const f32x4 bf = *(const f32x4*)&sB1[16 * mt + 4 * g];
                const f16x8 a = *(const f16x8*)(sW1 + (16 * mt + lh) * 64 + ((g ^ (lh & 3)) << 4));
                f32x4 c = __builtin_amdgcn_mfma_f32_16x16x32_f16(a, bx, bf, 0, 0, 0);
                bh1[mt] = pkh(c);   // D rows 4g+r == B k 4g+e for k-step mt
            }
            // ---- L2 (4 x 16x16x16) + fused VALU sigma partial ----
            f16x4 bh2[4];
            float sp = 0.f;
            #pragma unroll
            for (int mt = 0; mt < 4; ++mt) {
                const int row = (16 * mt + lh) * 128;
                const f16x4 a0 = *(const f16x4*)(sW2 + row + (((0 + g) ^ swz8) << 3));
                const f16x4 a1 = *(const f16x4*)(sW2 + row + (((4 + g) ^ swz8) << 3));
                const f16x4 a2 = *(const f16x4*)(sW2 + row + (((8 + g) ^ swz8) << 3));
                const f16x4 a3 = *(const f16x4*)(sW2 + row + (((12 + g) ^ swz8) << 3));
                const f32x4 bf = *(const f32x4*)&sB2[16 * mt + 4 * g];
                const f32x4 ws = *(const f32x4*)&sWs[16 * mt + 4 * g];
                f32x4 c = __builtin_amdgcn_mfma_f32_16x16x16f16(a0, bh1[0], bf, 0, 0, 0);
                c = __builtin_amdgcn_mfma_f32_16x16x16f16(a1, bh1[1], c, 0, 0, 0);
                c = __builtin_amdgcn_mfma_f32_16x16x16f16(a2, bh1[2], c, 0, 0, 0);
                c = __builtin_amdgcn_mfma_f32_16x16x16f16(a3, bh1[3], c, 0, 0, 0);
                const float r0 = fmaxf(c[0], 0.f), r1 = fmaxf(c[1], 0.f);
                const float r2 = fmaxf(c[2], 0.f), r3 = fmaxf(c[3], 0.f);
                sp += ws[0] * r0 + ws[1] * r1 + ws[2] * r2 + ws[3] * r3;
                uint2 u; u.x = pk2(r0, r1); u.y = pk2(r2, r3);
                bh2[mt] = __builtin_bit_cast(f16x4, u);
            }
            // ---- Wc layer (C = pd + bc) + FUSED rgb head ----
            f32x4 accC;
            #pragma unroll
            for (int mt = 0; mt < 4; ++mt) {
                const int row = (16 * mt + lh) * 128;
                const f16x4 a0 = *(const f16x4*)(sWc + row + (((0 + g) ^ swz8) << 3));
                const f16x4 a1 = *(const f16x4*)(sWc + row + (((4 + g) ^ swz8) << 3));
                const f16x4 a2 = *(const f16x4*)(sWc + row + (((8 + g) ^ swz8) << 3));
                const f16x4 a3 = *(const f16x4*)(sWc + row + (((12 + g) ^ swz8) << 3));
                const f32x4 pdf = *(const f32x4*)&sPdB[wid][16 * mt + 4 * g];
                const f16x4 aC = *(const f16x4*)(sHC + lh * 128 + (((4 * mt + g) ^ swz8) << 3));
                f32x4 c = __builtin_amdgcn_mfma_f32_16x16x16f16(a0, bh2[0], pdf, 0, 0, 0);
                c = __builtin_amdgcn_mfma_f32_16x16x16f16(a1, bh2[1], c, 0, 0, 0);
                c = __builtin_amdgcn_mfma_f32_16x16x16f16(a2, bh2[2], c, 0, 0, 0);
                c = __builtin_amdgcn_mfma_f32_16x16x16f16(a3, bh2[3], c, 0, 0, 0);
                const f16x4 bgf = pkh(c);
                f32x4 ca = (mt == 0) ? f32x4{0.f, 0.f, 0.f, 0.f} : accC;
                accC = __builtin_amdgcn_mfma_f32_16x16x16f16(aC, bgf, ca, 0, 0, 0);
            }
            // ---- sigma reduce over g-groups (all lanes get full sum) ----
            sp += __shfl_xor(sp, 16);
            sp += __shfl_xor(sp, 32);
            // ---- rgb extraction: row 4g+j has color (g+j)%3 ----
            const float crS = (g == 1) ? accC[2] : (g == 2) ? accC[1] : accC[0];
            const float cgS = (g == 0) ? accC[1] : (g == 1) ? accC[0]
                            : (g == 2) ? accC[2] : accC[1];
            const float cbS = (g == 0) ? accC[2] : (g == 1) ? accC[1]
                            : (g == 2) ? accC[0] : accC[2];

            const float sigma = valid ? fmaxf(sp + bsV, 0.f) : 0.f;
            const float rC = 1.f / (1.f + __expf(-(crS + br0)));
            const float gC = 1.f / (1.f + __expf(-(cgS + br1)));
            const float bC = 1.f / (1.f + __expf(-(cbS + br2)));

            // ---- compositing over this tile (carry via f, exact) ----
            const float sdelta = sigma * STEPf;
            float scan = sdelta;
            #pragma unroll
            for (int off = 1; off < 16; off <<= 1) {
                const float n = __shfl_up(scan, off);
                if (lh >= off) scan += n;
            }
            const float T     = __expf(-(scan - sdelta));
            const float alpha = 1.f - __expf(-sdelta);
            const float w = f * T * alpha;          // tile factor folded per-lane
            W  += w;
            WT += w * tS;
            Rr += w * rC;
            Gg += w * gC;
            Bb += w * bC;
            const float Stile = rfl(__shfl(scan, (lane & 48) | 15));  // tile sigma-sum
            f *= __expf(-Stile);
            if (f < 6e-6f) break;                   // transmittance exhausted
        }
    }

    // ---- ONE reduce over the 16 lh lanes per ray (values g-replicated) ----
    #pragma unroll
    for (int off = 1; off < 16; off <<= 1) {
        W  += __shfl_xor(W,  off);
        WT += __shfl_xor(WT, off);
        Rr += __shfl_xor(Rr, off);
        Gg += __shfl_xor(Gg, off);
        Bb += __shfl_xor(Bb, off);
    }
    if (lane == 0) {
        const float bg_ = 1.f - W;
        out[ray * 3 + 0] = Rr + bg_;
        out[ray * 3 + 1] = Gg + bg_;
        out[ray * 3 + 2] = Bb + bg_;
        out[3 * nrays + ray] = WT;
        out[4 * nrays + ray] = W;
    }
}

extern "C" void kernel_launch(void* const* d_in, const int* in_sizes, int n_in,
                              void* d_out, int out_size, void* d_ws, size_t ws_size,
                              hipStream_t stream) {
    const float* rays_o   = (const float*)d_in[0];
    const float* viewdirs = (const float*)d_in[1];
    const void*  occ      = (const void*) d_in[2];
    const float* W1 = (const float*)d_in[3];
    const float* b1 = (const float*)d_in[4];
    const float* W2 = (const float*)d_in[5];
    const float* b2 = (const float*)d_in[6];
    const float* Ws = (const float*)d_in[7];
    const float* bs = (const float*)d_in[8];
    const float* Wc = (const float*)d_in[9];
    const float* Wd = (const float*)d_in[10];
    const float* bc = (const float*)d_in[11];
    const float* Wr = (const float*)d_in[12];
    const float* br = (const float*)d_in[13];
    float* out = (float*)d_out;

    const int nrays = in_sizes[0] / 3;
    const int nblocks = (nrays + 7) / 8;     // 8 rays (waves) per 512-thread block
                                             // nrays=8192 -> 1024 = whole grid resident

    nerf_mfma<<<nblocks, 512, 0, stream>>>(rays_o, viewdirs, occ,
                                           W1, b1, W2, b2, Ws, bs, Wc, Wd, bc, Wr, br,
                                           out, nrays);
}